// Round 13
// baseline (459.273 us; speedup 1.0000x reference)
//
#include <hip/hip_runtime.h>

typedef __bf16 bf16x8 __attribute__((ext_vector_type(8)));
typedef float f32x4 __attribute__((ext_vector_type(4)));
typedef unsigned short u16;
typedef unsigned int u32;
typedef u16 u16x8 __attribute__((ext_vector_type(8)));
typedef u16 u16x4 __attribute__((ext_vector_type(4)));

// B=16, SV=1024, ST=512, D=768, H=8, DH=96. Chunked over CH batches,
// R = CH*1536 rows (CH*1024 visual then CH*512 text).

__device__ __forceinline__ u16 f2bf(float f) {
    u32 u = __builtin_bit_cast(u32, f);
    u32 r = u + 0x7FFFu + ((u >> 16) & 1u);
    return (u16)(r >> 16);
}

__device__ __forceinline__ float bf2f(u16 b) {
    u32 u = ((u32)b) << 16;
    return __builtin_bit_cast(float, u);
}

__device__ __forceinline__ f32x4 mfma16(bf16x8 a, bf16x8 b, f32x4 c) {
    return __builtin_amdgcn_mfma_f32_16x16x32_bf16(a, b, c, 0, 0, 0);
}

#define GLOAD_LDS16(g, l) __builtin_amdgcn_global_load_lds( \
    (__attribute__((address_space(1))) void*)(g), \
    (__attribute__((address_space(3))) void*)(l), 16, 0, 0)

// ---------- prep kernels ----------

__global__ __launch_bounds__(256) void k_cvt_x(const float* __restrict__ vf,
                                               const float* __restrict__ tf,
                                               u16* __restrict__ X, int nvis4) {
    int i = blockIdx.x * 256 + threadIdx.x;
    f32x4 v = (i < nvis4) ? ((const f32x4*)vf)[i] : ((const f32x4*)tf)[i - nvis4];
    u16x4 o = { f2bf(v[0]), f2bf(v[1]), f2bf(v[2]), f2bf(v[3]) };
    ((u16x4*)X)[i] = o;
}

// src f32 [K0][N0] -> dst bf16 [N0][K0]   (64x64 LDS tiles)
__global__ __launch_bounds__(256) void k_transpose(const float* __restrict__ src,
                                                   u16* __restrict__ dst,
                                                   int K0, int N0) {
    __shared__ float t[64][65];
    int ntx = N0 >> 6;
    int k0 = (blockIdx.x / ntx) << 6, n0 = (blockIdx.x % ntx) << 6;
    int c = threadIdx.x & 63, rr = threadIdx.x >> 6;
#pragma unroll
    for (int q = 0; q < 16; q++) {
        int r = q * 4 + rr;
        t[r][c] = src[(size_t)(k0 + r) * N0 + n0 + c];
    }
    __syncthreads();
#pragma unroll
    for (int q = 0; q < 16; q++) {
        int r = q * 4 + rr;
        dst[(size_t)(n0 + r) * K0 + k0 + c] = f2bf(t[c][r]);
    }
}

__global__ __launch_bounds__(256) void k_bias(const float* __restrict__ bq,
                                              const float* __restrict__ bk,
                                              const float* __restrict__ bv,
                                              float* __restrict__ bqkv) {
    int n = blockIdx.x * 256 + threadIdx.x;
    if (n < 2304) {
        const float* s = (n < 768) ? bq : ((n < 1536) ? bk : bv);
        int r = (n < 768) ? n : ((n < 1536) ? n - 768 : n - 1536);
        bqkv[n] = s[r];
    }
}

__global__ __launch_bounds__(256) void k_zero(float* __restrict__ p) {
    p[blockIdx.x * 256 + threadIdx.x] = 0.f;
}

// ---------- GEMM: C[R][N] = A[R][K] * Bt[N][K]^T + bias (+residual) ----------
// XCD-chunked blockIdx swizzle (grid always a multiple of 8).
// 2-phase pipeline (attn-proven sync): LDS double-buffered, ONE barrier per
// K-step, stage(kt+1) issued right after the barrier so load latency hides
// under the current 16 MFMA.
// SPLIT_VT: blocks with n0>=1536 (V columns) write accumulators TRANSPOSED
// directly into VtG[(col-1536)*Rtot + row] as u16x4 row-runs.
template <bool OUT_BF16, bool ADD_RES, bool SPLIT_VT>
__global__ __launch_bounds__(256) void k_gemm(const u16* __restrict__ A,
                                              const u16* __restrict__ Bt,
                                              const float* __restrict__ bias,
                                              const float* __restrict__ resA,
                                              const float* __restrict__ resB,
                                              void* __restrict__ Cout,
                                              int Ndim, int Kdim, int mvisL,
                                              u16* __restrict__ VtGp, int Rtot) {
    __shared__ alignas(16) u16 sA[2][128 * 32];
    __shared__ alignas(16) u16 sB[2][128 * 32];
    const int tid = threadIdx.x, wid = tid >> 6, lane = tid & 63;
    const int nwg = gridDim.x;
    const int wg = (blockIdx.x & 7) * (nwg >> 3) + (blockIdx.x >> 3);
    const int ntiles = Ndim >> 7;
    const int mt = wg / ntiles, nt = wg - mt * ntiles;
    const int m0 = mt << 7, n0 = nt << 7;
    const int wm = wid >> 1, wn = wid & 1;
    f32x4 acc[4][4] = {};

    const int r0 = tid >> 2, p0 = tid & 3;
    const int r1 = 64 + r0;
    const u16* ga0 = A + (size_t)(m0 + r0) * Kdim + p0 * 8;
    const u16* ga1 = A + (size_t)(m0 + r1) * Kdim + p0 * 8;
    const u16* gb0 = Bt + (size_t)(n0 + r0) * Kdim + p0 * 8;
    const u16* gb1 = Bt + (size_t)(n0 + r1) * Kdim + p0 * 8;
    const int loff0 = wid * 512;          // rows 0..63 region (u16 units)
    const int loff1 = 2048 + wid * 512;   // rows 64..127 region

    const int arow = (wm << 6) + (lane & 15);
    const int brow = (wn << 6) + (lane & 15);
    const int kg = (lane >> 4) * 8;

    auto stage = [&](int kt, int pb) {
        GLOAD_LDS16(ga0 + kt, &sA[pb][loff0]);
        GLOAD_LDS16(ga1 + kt, &sA[pb][loff1]);
        GLOAD_LDS16(gb0 + kt, &sB[pb][loff0]);
        GLOAD_LDS16(gb1 + kt, &sB[pb][loff1]);
    };

    const int niter = Kdim >> 5;
    stage(0, 0);
    for (int it = 0; it < niter; ++it) {
        const int cur = it & 1;
        __syncthreads();                  // stage(it) complete; prev reads of cur done
        if (it + 1 < niter) stage((it + 1) << 5, cur ^ 1);
        bf16x8 av[4], bw[4];
#pragma unroll
        for (int i = 0; i < 4; i++) av[i] = *(const bf16x8*)&sA[cur][(arow + i * 16) * 32 + kg];
#pragma unroll
        for (int j = 0; j < 4; j++) bw[j] = *(const bf16x8*)&sB[cur][(brow + j * 16) * 32 + kg];
#pragma unroll
        for (int i = 0; i < 4; i++)
#pragma unroll
            for (int j = 0; j < 4; j++) acc[i][j] = mfma16(av[i], bw[j], acc[i][j]);
    }

    const int col0 = n0 + (wn << 6) + (lane & 15);
    const int rowb = m0 + (wm << 6) + ((lane >> 4) << 2);
    float bvals[4];
#pragma unroll
    for (int j = 0; j < 4; j++) bvals[j] = bias[col0 + j * 16];

    if constexpr (SPLIT_VT) {
        if (n0 >= 1536) {     // V block: transposed write to VtG, skip normal C
            const int vcol0 = col0 - 1536;
#pragma unroll
            for (int i = 0; i < 4; i++) {
#pragma unroll
                for (int j = 0; j < 4; j++) {
                    u16x4 o4;
#pragma unroll
                    for (int rg = 0; rg < 4; rg++) o4[rg] = f2bf(acc[i][j][rg] + bvals[j]);
                    *(u16x4*)&VtGp[(size_t)(vcol0 + j * 16) * Rtot + rowb + i * 16] = o4;
                }
            }
            return;
        }
    }

#pragma unroll
    for (int i = 0; i < 4; i++) {
#pragma unroll
        for (int rg = 0; rg < 4; rg++) {
            const int row = rowb + i * 16 + rg;
            const float* rp = nullptr;
            if constexpr (ADD_RES)
                rp = (row < mvisL) ? resA + (size_t)row * 768
                                   : resB + (size_t)(row - mvisL) * 768;
#pragma unroll
            for (int j = 0; j < 4; j++) {
                const int col = col0 + j * 16;
                float v = acc[i][j][rg] + bvals[j];
                if constexpr (ADD_RES) v += rp[col];
                if constexpr (OUT_BF16)
                    ((u16*)Cout)[(size_t)row * Ndim + col] = f2bf(v);
                else
                    ((float*)Cout)[(size_t)row * Ndim + col] = v;
            }
        }
    }
}

// ---------- fused cross-attention (exact R7 kernel: best validated, 147us) ----------
// One block per (b,h,direction). 256 q-rows per K/V pass (2 q-sets of 128).
// j-outer QK^T: each K fragment read from LDS once, feeds both q-sets.
// K/V double-buffered, ONE barrier per step, stage(s+1) issued after barrier.
__global__ __launch_bounds__(512) void k_attn(const u16* __restrict__ qkv,
                                              const u16* __restrict__ VtG,
                                              const int* __restrict__ vmaskc,
                                              const int* __restrict__ tmaskc,
                                              u16* __restrict__ attn, int CHn, int Rtot) {
    __shared__ alignas(16) u16 Kl[2][128 * 128];   // 64 KB
    __shared__ alignas(16) u16 Vt[2][96 * 128];    // 48 KB
    __shared__ alignas(16) u16 Pl[8][16 * 128];    // 32 KB
    __shared__ float mk[2][128];

    const int bx = blockIdx.x;
    int b, h, qbase, kbase, nqt, ntl;
    const int* mask;
    const int vcap = CHn * 8;
    if (bx < vcap) {   // visual queries attend to text: 4 passes x 256 rows
        b = bx >> 3; h = bx & 7;
        qbase = b << 10; kbase = (CHn << 10) + (b << 9);
        mask = tmaskc + (b << 9); nqt = 4; ntl = 2;   // ntile=4 (Sk=512)
    } else {           // text queries attend to visual: 2 passes x 256 rows
        const int bx2 = bx - vcap;
        b = bx2 >> 3; h = bx2 & 7;
        qbase = (CHn << 10) + (b << 9); kbase = b << 10;
        mask = vmaskc + (b << 10); nqt = 2; ntl = 3;  // ntile=8 (Sk=1024)
    }
    const int ntile = 1 << ntl;
    const int nsteps = nqt << ntl;
    const int tid = threadIdx.x, wid = tid >> 6, lane = tid & 63;
    const int l15 = lane & 15, l4 = lane >> 4;
    const float scale = 0.10206207261596577f;  // 1/sqrt(96)

    int koff[4];
#pragma unroll
    for (int kk = 0; kk < 4; kk++) koff[kk] = ((kk * 4 + l4) ^ (l15 & 7)) << 3;

    auto kt_of = [&](int s) {
        const int qt = s >> ntl, ktr = s & (ntile - 1);
        return (qt & 1) ? (ntile - 1 - ktr) : ktr;   // serpentine
    };
    auto stage = [&](int kt, int pb) {
#pragma unroll
        for (int it = 0; it < 4; ++it) {             // K tile: 2048 16B chunks
            const int cb = it * 512 + (wid << 6);
            const int c = cb + lane;
            const int r = c >> 4, s8 = c & 15;
            const int k8 = s8 ^ (r & 7);
            const u16* src = qkv + (size_t)(kbase + (kt << 7) + r) * 2304 + 768 + h * 96
                             + (k8 < 12 ? k8 * 8 : 0);
            GLOAD_LDS16(src, &Kl[pb][(size_t)cb * 8]);
        }
#pragma unroll
        for (int it = 0; it < 3; ++it) {             // V tile: 1536 16B chunks
            const int cb = it * 512 + (wid << 6);
            const int c = cb + lane;
            const int d = c >> 4, s8 = c & 15;
            const int k8 = s8 ^ (d & 7);
            const u16* src = VtG + (size_t)(h * 96 + d) * Rtot + kbase + (kt << 7) + k8 * 8;
            GLOAD_LDS16(src, &Vt[pb][(size_t)cb * 8]);
        }
        if (tid < 128) mk[pb][tid] = mask[(kt << 7) + tid] ? 0.f : -1e30f;
    };

    stage(kt_of(0), 0);
    int s = 0;
    for (int qt = 0; qt < nqt; ++qt) {
        bf16x8 aq[2][3];
#pragma unroll
        for (int qs = 0; qs < 2; ++qs) {
            const int qr = qbase + (qt << 8) + (wid << 5) + qs * 16 + l15;
#pragma unroll
            for (int kk = 0; kk < 3; kk++) {
                bf16x8 tq = *(const bf16x8*)&qkv[(size_t)qr * 2304 + h * 96 + kk * 32 + l4 * 8];
#pragma unroll
                for (int e = 0; e < 8; e++) tq[e] = (__bf16)((float)tq[e] * scale);
                aq[qs][kk] = tq;
            }
        }
        f32x4 o[2][6] = {};
        float mrun[2][4], lrun[2][4];
#pragma unroll
        for (int qs = 0; qs < 2; ++qs)
#pragma unroll
            for (int rg = 0; rg < 4; rg++) { mrun[qs][rg] = -1e30f; lrun[qs][rg] = 0.f; }

        for (int ktr = 0; ktr < ntile; ++ktr, ++s) {
            const int cur = s & 1;
            __syncthreads();                      // publish stage(cur); reads of cur^1 done
            if (s + 1 < nsteps) stage(kt_of(s + 1), cur ^ 1);

            // ---- S = Q K^T, j-outer ----
            f32x4 sc[2][8];
#pragma unroll
            for (int j = 0; j < 8; j++) {
                const int rbase = (j * 16 + l15) * 128;
                bf16x8 bk[3];
#pragma unroll
                for (int kk = 0; kk < 3; kk++)
                    bk[kk] = *(const bf16x8*)&Kl[cur][rbase + koff[kk]];
#pragma unroll
                for (int qs = 0; qs < 2; ++qs) {
                    f32x4 cj = {0.f, 0.f, 0.f, 0.f};
#pragma unroll
                    for (int kk = 0; kk < 3; kk++) cj = mfma16(aq[qs][kk], bk[kk], cj);
                    sc[qs][j] = cj;
                }
            }

#pragma unroll
            for (int qs = 0; qs < 2; ++qs) {
                float tmax[4] = {-1e30f, -1e30f, -1e30f, -1e30f};
#pragma unroll
                for (int j = 0; j < 8; j++) {
                    float mb = mk[cur][j * 16 + l15];
#pragma unroll
                    for (int rg = 0; rg < 4; rg++) {
                        float v = sc[qs][j][rg] + mb;
                        sc[qs][j][rg] = v;
                        tmax[rg] = fmaxf(tmax[rg], v);
                    }
                }
#pragma unroll
                for (int d = 1; d < 16; d <<= 1)
#pragma unroll
                    for (int rg = 0; rg < 4; rg++)
                        tmax[rg] = fmaxf(tmax[rg], __shfl_xor(tmax[rg], d));
                int need = 0;
#pragma unroll
                for (int rg = 0; rg < 4; rg++) need |= (tmax[rg] > mrun[qs][rg] + 8.f) ? 1 : 0;
                if (__any(need)) {
#pragma unroll
                    for (int rg = 0; rg < 4; rg++) {
                        float mn = fmaxf(mrun[qs][rg], tmax[rg]);
                        float corr = __expf(mrun[qs][rg] - mn);
                        mrun[qs][rg] = mn;
                        lrun[qs][rg] *= corr;
#pragma unroll
                        for (int j6 = 0; j6 < 6; j6++) o[qs][j6][rg] *= corr;
                    }
                }
                float tsum[4] = {0.f, 0.f, 0.f, 0.f};
#pragma unroll
                for (int j = 0; j < 8; j++)
#pragma unroll
                    for (int rg = 0; rg < 4; rg++) {
                        float p = __expf(sc[qs][j][rg] - mrun[qs][rg]);
                        tsum[rg] += p;
                        const int prow = l4 * 4 + rg;
                        Pl[wid][prow * 128 + ((j * 16 + l15) ^ ((prow & 7) << 3))] = f2bf(p);
                    }
#pragma unroll
                for (int d = 1; d < 16; d <<= 1)
#pragma unroll
                    for (int rg = 0; rg < 4; rg++) tsum[rg] += __shfl_xor(tsum[rg], d);
#pragma unroll
                for (int rg = 0; rg < 4; rg++) lrun[qs][rg] += tsum[rg];

                // ---- O += P V ----
#pragma unroll
                for (int kk = 0; kk < 4; kk++) {
                    bf16x8 ap = *(const bf16x8*)&Pl[wid][l15 * 128 + koff[kk]];
#pragma unroll
                    for (int j6 = 0; j6 < 6; j6++) {
                        bf16x8 bv8 = *(const bf16x8*)&Vt[cur][(j6 * 16 + l15) * 128 + koff[kk]];
                        o[qs][j6] = mfma16(ap, bv8, o[qs][j6]);
                    }
                }
            }
        }

#pragma unroll
        for (int qs = 0; qs < 2; ++qs) {
            float inv[4];
#pragma unroll
            for (int rg = 0; rg < 4; rg++) inv[rg] = 1.f / lrun[qs][rg];
            const size_t orow = (size_t)(qbase + (qt << 8) + (wid << 5) + qs * 16);
#pragma unroll
            for (int j6 = 0; j6 < 6; j6++)
#pragma unroll
                for (int rg = 0; rg < 4; rg++)
                    attn[(orow + l4 * 4 + rg) * 768 + h * 96 + j6 * 16 + l15] =
                        f2bf(o[qs][j6][rg] * inv[rg]);
        }
    }
}

// ---------- LN1 + masked-pool accumulation (bf16 input) ----------
__global__ __launch_bounds__(256) void k_ln_pool(const u16* __restrict__ X,
                                                 const int* __restrict__ vmaskc,
                                                 const int* __restrict__ tmaskc,
                                                 const float* __restrict__ g,
                                                 const float* __restrict__ bb,
                                                 float* __restrict__ pooled,
                                                 int mvisL, int bg0) {
    __shared__ float pool[768];
    const int tid = threadIdx.x, wid = tid >> 6, lane = tid & 63;
    const int row0 = blockIdx.x << 5;
    const bool vis = row0 < mvisL;
    const int* mask = vis ? vmaskc : tmaskc;
    const int mbase = vis ? 0 : mvisL;
    const int bl = vis ? (row0 >> 10) : ((row0 - mvisL) >> 9);
    float* pout = pooled + (vis ? 0 : 12288) + (size_t)(bg0 + bl) * 768;

    float gv[12], bv2[12];
#pragma unroll
    for (int k = 0; k < 12; k++) { gv[k] = g[lane + k * 64]; bv2[k] = bb[lane + k * 64]; }
    float acc[12] = {};
    for (int rr = 0; rr < 8; ++rr) {
        const int row = row0 + (wid << 3) + rr;
        const u16* x = X + (size_t)row * 768;
        float xs[12], sm = 0.f, s2 = 0.f;
#pragma unroll
        for (int k = 0; k < 12; k++) {
            float tv = bf2f(x[lane + k * 64]);
            xs[k] = tv; sm += tv; s2 += tv * tv;
        }
#pragma unroll
        for (int d = 1; d < 64; d <<= 1) { sm += __shfl_xor(sm, d); s2 += __shfl_xor(s2, d); }
        const float mean = sm * (1.f / 768.f);
        const float rstd = rsqrtf(s2 * (1.f / 768.f) - mean * mean + 1e-5f);
        const float mv = (float)mask[row - mbase];
#pragma unroll
        for (int k = 0; k < 12; k++) acc[k] += ((xs[k] - mean) * rstd * gv[k] + bv2[k]) * mv;
    }
    pool[tid] = 0.f; pool[tid + 256] = 0.f; pool[tid + 512] = 0.f;
    __syncthreads();
#pragma unroll
    for (int k = 0; k < 12; k++) atomicAdd(&pool[lane + k * 64], acc[k]);
    __syncthreads();
    atomicAdd(&pout[tid], pool[tid]);
    atomicAdd(&pout[tid + 256], pool[tid + 256]);
    atomicAdd(&pout[tid + 512], pool[tid + 512]);
}

// ---------- final ----------
__device__ __forceinline__ float blk_sum(float v, volatile float* tmp) {
#pragma unroll
    for (int d = 1; d < 64; d <<= 1) v += __shfl_xor(v, d);
    __syncthreads();
    if ((threadIdx.x & 63) == 0) tmp[threadIdx.x >> 6] = v;
    __syncthreads();
    return tmp[0] + tmp[1] + tmp[2] + tmp[3];
}

__global__ __launch_bounds__(256) void k_final(const float* __restrict__ pooled,
                                               const int* __restrict__ vmask,
                                               const int* __restrict__ tmask,
                                               const float* __restrict__ Wf,
                                               const float* __restrict__ bfv,
                                               const float* __restrict__ g2,
                                               const float* __restrict__ b2,
                                               float* __restrict__ out) {
    __shared__ float sh[1536];
    __shared__ float red[4];
    const int b = blockIdx.x, tid = threadIdx.x;
    float cv = 0.f, ct = 0.f;
    for (int i = tid; i < 1024; i += 256) cv += (float)vmask[(b << 10) + i];
    for (int i = tid; i < 512; i += 256) ct += (float)tmask[(b << 9) + i];
    cv = blk_sum(cv, red);
    ct = blk_sum(ct, red);
    const float iv = 1.f / cv, itv = 1.f / ct;
#pragma unroll
    for (int k = 0; k < 3; k++) {
        int j = tid + (k << 8);
        sh[j] = pooled[b * 768 + j] * iv;
        sh[768 + j] = pooled[12288 + b * 768 + j] * itv;
    }
    __syncthreads();
    float f0 = bfv[tid], f1 = bfv[tid + 256], f2 = bfv[tid + 512];
    for (int i = 0; i < 1536; i++) {
        const float pv = sh[i];
        const float* w = Wf + (size_t)i * 768;
        f0 += pv * w[tid];
        f1 += pv * w[tid + 256];
        f2 += pv * w[tid + 512];
    }
    float sm = blk_sum(f0 + f1 + f2, red);
    float s2 = blk_sum(f0 * f0 + f1 * f1 + f2 * f2, red);
    const float mean = sm * (1.f / 768.f);
    const float rstd = rsqrtf(s2 * (1.f / 768.f) - mean * mean + 1e-5f);
    out[b * 768 + tid] = (f0 - mean) * rstd * g2[tid] + b2[tid];
    out[b * 768 + tid + 256] = (f1 - mean) * rstd * g2[tid + 256] + b2[tid + 256];
    out[b * 768 + tid + 512] = (f2 - mean) * rstd * g2[tid + 512] + b2[tid + 512];
}

// ---------- host ----------
extern "C" void kernel_launch(void* const* d_in, const int* in_sizes, int n_in,
                              void* d_out, int out_size, void* d_ws, size_t ws_size,
                              hipStream_t stream) {
    (void)in_sizes; (void)n_in; (void)out_size;
    const float* vf = (const float*)d_in[0];
    const float* tf = (const float*)d_in[1];
    const int* vmask = (const int*)d_in[2];
    const int* tmask = (const int*)d_in[3];
    const float* Wq = (const float*)d_in[4];
    const float* bq = (const float*)d_in[5];
    const float* Wk = (const float*)d_in[6];
    const float* bk = (const float*)d_in[7];
    const float* Wv = (const float*)d_in[8];
    const float* bv = (const float*)d_in[9];
    const float* Wo = (const float*)d_in[10];
    const float* bo = (const float*)d_in[11];
    const float* g1 = (const float*)d_in[12];
    const float* b1 = (const float*)d_in[13];
    const float* Wf = (const float*)d_in[14];
    const float* bfv = (const float*)d_in[15];
    const float* g2 = (const float*)d_in[16];
    const float* b2 = (const float*)d_in[17];
    float* outp = (float*)d_out;

    // footprint = 4,826,112 + CH * (2,359,296 X + 7,077,888 QKV + 2,359,296 VtG)
    int CH = 16;
    while (CH > 1 && 4826112ull + (size_t)CH * 11796480ull > ws_size) CH >>= 1;
    const int NC = 16 / CH;
    const int Rtot = CH * 1536;

    char* ws = (char*)d_ws;
    u16*   wsW      = (u16*)(ws);
    u16*   wsWo     = (u16*)(ws + 3538944);
    float* wsBqkv   = (float*)(ws + 4718592);
    float* wsPooled = (float*)(ws + 4727808);
    u16*   wsX      = (u16*)(ws + 4826112);                 // [R][768] bf16 (reused: attn out)
    char*  qkvBase  = ws + 4826112 + (size_t)CH * 2359296;
    u16*   wsQKV    = (u16*)qkvBase;                         // [R][2304] bf16 (reused: Oproj bf16)
    u16*   wsOproj  = (u16*)qkvBase;
    u16*   wsVtG    = (u16*)(qkvBase + (size_t)CH * 7077888);// [768][R] bf16
    u16*   wsAttn   = wsX;

    k_transpose<<<dim3(144), dim3(256), 0, stream>>>(Wq, wsW, 768, 768);
    k_transpose<<<dim3(144), dim3(256), 0, stream>>>(Wk, wsW + 589824, 768, 768);
    k_transpose<<<dim3(144), dim3(256), 0, stream>>>(Wv, wsW + 1179648, 768, 768);
    k_transpose<<<dim3(144), dim3(256), 0, stream>>>(Wo, wsWo, 768, 768);
    k_bias<<<dim3(9), dim3(256), 0, stream>>>(bq, bk, bv, wsBqkv);
    k_zero<<<dim3(96), dim3(256), 0, stream>>>(wsPooled);

    for (int c = 0; c < NC; ++c) {
        const float* vfc = vf + (size_t)c * CH * 1024 * 768;
        const float* tfc = tf + (size_t)c * CH * 512 * 768;
        const int* vmc = vmask + c * CH * 1024;
        const int* tmc = tmask + c * CH * 512;

        k_cvt_x<<<dim3(CH * 1152), dim3(256), 0, stream>>>(vfc, tfc, wsX, CH * 196608);

        // QKV GEMM; V third written transposed directly into VtG
        k_gemm<true, false, true><<<dim3(CH * 216), dim3(256), 0, stream>>>(
            wsX, wsW, wsBqkv, nullptr, nullptr, (void*)wsQKV, 2304, 768, 0, wsVtG, Rtot);

        k_attn<<<dim3(CH * 16), dim3(512), 0, stream>>>(
            wsQKV, wsVtG, vmc, tmc, wsAttn, CH, Rtot);

        // O-proj + bias + residual, bf16 out
        k_gemm<true, true, false><<<dim3(CH * 72), dim3(256), 0, stream>>>(
            wsAttn, wsWo, bo, vfc, tfc, (void*)wsOproj, 768, 768, CH * 1024, nullptr, 0);

        k_ln_pool<<<dim3(CH * 48), dim3(256), 0, stream>>>(
            wsOproj, vmc, tmc, g1, b1, wsPooled, CH * 1024, c * CH);
    }

    k_final<<<dim3(16), dim3(256), 0, stream>>>(wsPooled, vmask, tmask, Wf, bfv, g2, b2, outp);
}

// Round 14
// 454.838 us; speedup vs baseline: 1.0098x; 1.0098x over previous
//
#include <hip/hip_runtime.h>

typedef __bf16 bf16x8 __attribute__((ext_vector_type(8)));
typedef float f32x4 __attribute__((ext_vector_type(4)));
typedef unsigned short u16;
typedef unsigned int u32;
typedef u16 u16x8 __attribute__((ext_vector_type(8)));
typedef u16 u16x4 __attribute__((ext_vector_type(4)));

// B=16, SV=1024, ST=512, D=768, H=8, DH=96. Chunked over CH batches,
// R = CH*1536 rows (CH*1024 visual then CH*512 text).

__device__ __forceinline__ u16 f2bf(float f) {
    u32 u = __builtin_bit_cast(u32, f);
    u32 r = u + 0x7FFFu + ((u >> 16) & 1u);
    return (u16)(r >> 16);
}

__device__ __forceinline__ float bf2f(u16 b) {
    u32 u = ((u32)b) << 16;
    return __builtin_bit_cast(float, u);
}

__device__ __forceinline__ f32x4 mfma16(bf16x8 a, bf16x8 b, f32x4 c) {
    return __builtin_amdgcn_mfma_f32_16x16x32_bf16(a, b, c, 0, 0, 0);
}

#define GLOAD_LDS16(g, l) __builtin_amdgcn_global_load_lds( \
    (__attribute__((address_space(1))) void*)(g), \
    (__attribute__((address_space(3))) void*)(l), 16, 0, 0)

// ---------- prep kernels ----------

__global__ __launch_bounds__(256) void k_cvt_x(const float* __restrict__ vf,
                                               const float* __restrict__ tf,
                                               u16* __restrict__ X, int nvis4) {
    int i = blockIdx.x * 256 + threadIdx.x;
    f32x4 v = (i < nvis4) ? ((const f32x4*)vf)[i] : ((const f32x4*)tf)[i - nvis4];
    u16x4 o = { f2bf(v[0]), f2bf(v[1]), f2bf(v[2]), f2bf(v[3]) };
    ((u16x4*)X)[i] = o;
}

// src f32 [K0][N0] -> dst bf16 [N0][K0]   (64x64 LDS tiles)
__global__ __launch_bounds__(256) void k_transpose(const float* __restrict__ src,
                                                   u16* __restrict__ dst,
                                                   int K0, int N0) {
    __shared__ float t[64][65];
    int ntx = N0 >> 6;
    int k0 = (blockIdx.x / ntx) << 6, n0 = (blockIdx.x % ntx) << 6;
    int c = threadIdx.x & 63, rr = threadIdx.x >> 6;
#pragma unroll
    for (int q = 0; q < 16; q++) {
        int r = q * 4 + rr;
        t[r][c] = src[(size_t)(k0 + r) * N0 + n0 + c];
    }
    __syncthreads();
#pragma unroll
    for (int q = 0; q < 16; q++) {
        int r = q * 4 + rr;
        dst[(size_t)(n0 + r) * K0 + k0 + c] = f2bf(t[c][r]);
    }
}

__global__ __launch_bounds__(256) void k_bias(const float* __restrict__ bq,
                                              const float* __restrict__ bk,
                                              const float* __restrict__ bv,
                                              float* __restrict__ bqkv) {
    int n = blockIdx.x * 256 + threadIdx.x;
    if (n < 2304) {
        const float* s = (n < 768) ? bq : ((n < 1536) ? bk : bv);
        int r = (n < 768) ? n : ((n < 1536) ? n - 768 : n - 1536);
        bqkv[n] = s[r];
    }
}

__global__ __launch_bounds__(256) void k_zero(float* __restrict__ p) {
    p[blockIdx.x * 256 + threadIdx.x] = 0.f;
}

// ---------- GEMM: C[R][N] = A[R][K] * Bt[N][K]^T + bias (+residual) ----------
// XCD-chunked blockIdx swizzle (grid always a multiple of 8).
// 2-phase pipeline (attn-proven sync): LDS double-buffered, ONE barrier per
// K-step, stage(kt+1) issued right after the barrier so load latency hides
// under the current 16 MFMA.
// SPLIT_VT: blocks with n0>=1536 (V columns) write accumulators TRANSPOSED
// directly into VtG[(col-1536)*Rtot + row] as u16x4 row-runs.
template <bool OUT_BF16, bool ADD_RES, bool SPLIT_VT>
__global__ __launch_bounds__(256) void k_gemm(const u16* __restrict__ A,
                                              const u16* __restrict__ Bt,
                                              const float* __restrict__ bias,
                                              const float* __restrict__ resA,
                                              const float* __restrict__ resB,
                                              void* __restrict__ Cout,
                                              int Ndim, int Kdim, int mvisL,
                                              u16* __restrict__ VtGp, int Rtot) {
    __shared__ alignas(16) u16 sA[2][128 * 32];
    __shared__ alignas(16) u16 sB[2][128 * 32];
    const int tid = threadIdx.x, wid = tid >> 6, lane = tid & 63;
    const int nwg = gridDim.x;
    const int wg = (blockIdx.x & 7) * (nwg >> 3) + (blockIdx.x >> 3);
    const int ntiles = Ndim >> 7;
    const int mt = wg / ntiles, nt = wg - mt * ntiles;
    const int m0 = mt << 7, n0 = nt << 7;
    const int wm = wid >> 1, wn = wid & 1;
    f32x4 acc[4][4] = {};

    const int r0 = tid >> 2, p0 = tid & 3;
    const int r1 = 64 + r0;
    const u16* ga0 = A + (size_t)(m0 + r0) * Kdim + p0 * 8;
    const u16* ga1 = A + (size_t)(m0 + r1) * Kdim + p0 * 8;
    const u16* gb0 = Bt + (size_t)(n0 + r0) * Kdim + p0 * 8;
    const u16* gb1 = Bt + (size_t)(n0 + r1) * Kdim + p0 * 8;
    const int loff0 = wid * 512;          // rows 0..63 region (u16 units)
    const int loff1 = 2048 + wid * 512;   // rows 64..127 region

    const int arow = (wm << 6) + (lane & 15);
    const int brow = (wn << 6) + (lane & 15);
    const int kg = (lane >> 4) * 8;

    auto stage = [&](int kt, int pb) {
        GLOAD_LDS16(ga0 + kt, &sA[pb][loff0]);
        GLOAD_LDS16(ga1 + kt, &sA[pb][loff1]);
        GLOAD_LDS16(gb0 + kt, &sB[pb][loff0]);
        GLOAD_LDS16(gb1 + kt, &sB[pb][loff1]);
    };

    const int niter = Kdim >> 5;
    stage(0, 0);
    for (int it = 0; it < niter; ++it) {
        const int cur = it & 1;
        __syncthreads();                  // stage(it) complete; prev reads of cur done
        if (it + 1 < niter) stage((it + 1) << 5, cur ^ 1);
        bf16x8 av[4], bw[4];
#pragma unroll
        for (int i = 0; i < 4; i++) av[i] = *(const bf16x8*)&sA[cur][(arow + i * 16) * 32 + kg];
#pragma unroll
        for (int j = 0; j < 4; j++) bw[j] = *(const bf16x8*)&sB[cur][(brow + j * 16) * 32 + kg];
#pragma unroll
        for (int i = 0; i < 4; i++)
#pragma unroll
            for (int j = 0; j < 4; j++) acc[i][j] = mfma16(av[i], bw[j], acc[i][j]);
    }

    const int col0 = n0 + (wn << 6) + (lane & 15);
    const int rowb = m0 + (wm << 6) + ((lane >> 4) << 2);
    float bvals[4];
#pragma unroll
    for (int j = 0; j < 4; j++) bvals[j] = bias[col0 + j * 16];

    if constexpr (SPLIT_VT) {
        if (n0 >= 1536) {     // V block: transposed write to VtG, skip normal C
            const int vcol0 = col0 - 1536;
#pragma unroll
            for (int i = 0; i < 4; i++) {
#pragma unroll
                for (int j = 0; j < 4; j++) {
                    u16x4 o4;
#pragma unroll
                    for (int rg = 0; rg < 4; rg++) o4[rg] = f2bf(acc[i][j][rg] + bvals[j]);
                    *(u16x4*)&VtGp[(size_t)(vcol0 + j * 16) * Rtot + rowb + i * 16] = o4;
                }
            }
            return;
        }
    }

#pragma unroll
    for (int i = 0; i < 4; i++) {
#pragma unroll
        for (int rg = 0; rg < 4; rg++) {
            const int row = rowb + i * 16 + rg;
            const float* rp = nullptr;
            if constexpr (ADD_RES)
                rp = (row < mvisL) ? resA + (size_t)row * 768
                                   : resB + (size_t)(row - mvisL) * 768;
#pragma unroll
            for (int j = 0; j < 4; j++) {
                const int col = col0 + j * 16;
                float v = acc[i][j][rg] + bvals[j];
                if constexpr (ADD_RES) v += rp[col];
                if constexpr (OUT_BF16)
                    ((u16*)Cout)[(size_t)row * Ndim + col] = f2bf(v);
                else
                    ((float*)Cout)[(size_t)row * Ndim + col] = v;
            }
        }
    }
}

// ---------- fused cross-attention (exact R7 kernel: best validated, 147us) ----------
// One block per (b,h,direction). 256 q-rows per K/V pass (2 q-sets of 128).
// j-outer QK^T: each K fragment read from LDS once, feeds both q-sets.
// K/V double-buffered, ONE barrier per step, stage(s+1) issued after barrier.
__global__ __launch_bounds__(512) void k_attn(const u16* __restrict__ qkv,
                                              const u16* __restrict__ VtG,
                                              const int* __restrict__ vmaskc,
                                              const int* __restrict__ tmaskc,
                                              u16* __restrict__ attn, int CHn, int Rtot) {
    __shared__ alignas(16) u16 Kl[2][128 * 128];   // 64 KB
    __shared__ alignas(16) u16 Vt[2][96 * 128];    // 48 KB
    __shared__ alignas(16) u16 Pl[8][16 * 128];    // 32 KB
    __shared__ float mk[2][128];

    const int bx = blockIdx.x;
    int b, h, qbase, kbase, nqt, ntl;
    const int* mask;
    const int vcap = CHn * 8;
    if (bx < vcap) {   // visual queries attend to text: 4 passes x 256 rows
        b = bx >> 3; h = bx & 7;
        qbase = b << 10; kbase = (CHn << 10) + (b << 9);
        mask = tmaskc + (b << 9); nqt = 4; ntl = 2;   // ntile=4 (Sk=512)
    } else {           // text queries attend to visual: 2 passes x 256 rows
        const int bx2 = bx - vcap;
        b = bx2 >> 3; h = bx2 & 7;
        qbase = (CHn << 10) + (b << 9); kbase = b << 10;
        mask = vmaskc + (b << 10); nqt = 2; ntl = 3;  // ntile=8 (Sk=1024)
    }
    const int ntile = 1 << ntl;
    const int nsteps = nqt << ntl;
    const int tid = threadIdx.x, wid = tid >> 6, lane = tid & 63;
    const int l15 = lane & 15, l4 = lane >> 4;
    const float scale = 0.10206207261596577f;  // 1/sqrt(96)

    int koff[4];
#pragma unroll
    for (int kk = 0; kk < 4; kk++) koff[kk] = ((kk * 4 + l4) ^ (l15 & 7)) << 3;

    auto kt_of = [&](int s) {
        const int qt = s >> ntl, ktr = s & (ntile - 1);
        return (qt & 1) ? (ntile - 1 - ktr) : ktr;   // serpentine
    };
    auto stage = [&](int kt, int pb) {
#pragma unroll
        for (int it = 0; it < 4; ++it) {             // K tile: 2048 16B chunks
            const int cb = it * 512 + (wid << 6);
            const int c = cb + lane;
            const int r = c >> 4, s8 = c & 15;
            const int k8 = s8 ^ (r & 7);
            const u16* src = qkv + (size_t)(kbase + (kt << 7) + r) * 2304 + 768 + h * 96
                             + (k8 < 12 ? k8 * 8 : 0);
            GLOAD_LDS16(src, &Kl[pb][(size_t)cb * 8]);
        }
#pragma unroll
        for (int it = 0; it < 3; ++it) {             // V tile: 1536 16B chunks
            const int cb = it * 512 + (wid << 6);
            const int c = cb + lane;
            const int d = c >> 4, s8 = c & 15;
            const int k8 = s8 ^ (d & 7);
            const u16* src = VtG + (size_t)(h * 96 + d) * Rtot + kbase + (kt << 7) + k8 * 8;
            GLOAD_LDS16(src, &Vt[pb][(size_t)cb * 8]);
        }
        if (tid < 128) mk[pb][tid] = mask[(kt << 7) + tid] ? 0.f : -1e30f;
    };

    stage(kt_of(0), 0);
    int s = 0;
    for (int qt = 0; qt < nqt; ++qt) {
        bf16x8 aq[2][3];
#pragma unroll
        for (int qs = 0; qs < 2; ++qs) {
            const int qr = qbase + (qt << 8) + (wid << 5) + qs * 16 + l15;
#pragma unroll
            for (int kk = 0; kk < 3; kk++) {
                bf16x8 tq = *(const bf16x8*)&qkv[(size_t)qr * 2304 + h * 96 + kk * 32 + l4 * 8];
#pragma unroll
                for (int e = 0; e < 8; e++) tq[e] = (__bf16)((float)tq[e] * scale);
                aq[qs][kk] = tq;
            }
        }
        f32x4 o[2][6] = {};
        float mrun[2][4], lrun[2][4];
#pragma unroll
        for (int qs = 0; qs < 2; ++qs)
#pragma unroll
            for (int rg = 0; rg < 4; rg++) { mrun[qs][rg] = -1e30f; lrun[qs][rg] = 0.f; }

        for (int ktr = 0; ktr < ntile; ++ktr, ++s) {
            const int cur = s & 1;
            __syncthreads();                      // publish stage(cur); reads of cur^1 done
            if (s + 1 < nsteps) stage(kt_of(s + 1), cur ^ 1);

            // ---- S = Q K^T, j-outer ----
            f32x4 sc[2][8];
#pragma unroll
            for (int j = 0; j < 8; j++) {
                const int rbase = (j * 16 + l15) * 128;
                bf16x8 bk[3];
#pragma unroll
                for (int kk = 0; kk < 3; kk++)
                    bk[kk] = *(const bf16x8*)&Kl[cur][rbase + koff[kk]];
#pragma unroll
                for (int qs = 0; qs < 2; ++qs) {
                    f32x4 cj = {0.f, 0.f, 0.f, 0.f};
#pragma unroll
                    for (int kk = 0; kk < 3; kk++) cj = mfma16(aq[qs][kk], bk[kk], cj);
                    sc[qs][j] = cj;
                }
            }

#pragma unroll
            for (int qs = 0; qs < 2; ++qs) {
                float tmax[4] = {-1e30f, -1e30f, -1e30f, -1e30f};
#pragma unroll
                for (int j = 0; j < 8; j++) {
                    float mb = mk[cur][j * 16 + l15];
#pragma unroll
                    for (int rg = 0; rg < 4; rg++) {
                        float v = sc[qs][j][rg] + mb;
                        sc[qs][j][rg] = v;
                        tmax[rg] = fmaxf(tmax[rg], v);
                    }
                }
#pragma unroll
                for (int d = 1; d < 16; d <<= 1)
#pragma unroll
                    for (int rg = 0; rg < 4; rg++)
                        tmax[rg] = fmaxf(tmax[rg], __shfl_xor(tmax[rg], d));
                int need = 0;
#pragma unroll
                for (int rg = 0; rg < 4; rg++) need |= (tmax[rg] > mrun[qs][rg] + 8.f) ? 1 : 0;
                if (__any(need)) {
#pragma unroll
                    for (int rg = 0; rg < 4; rg++) {
                        float mn = fmaxf(mrun[qs][rg], tmax[rg]);
                        float corr = __expf(mrun[qs][rg] - mn);
                        mrun[qs][rg] = mn;
                        lrun[qs][rg] *= corr;
#pragma unroll
                        for (int j6 = 0; j6 < 6; j6++) o[qs][j6][rg] *= corr;
                    }
                }
                float tsum[4] = {0.f, 0.f, 0.f, 0.f};
#pragma unroll
                for (int j = 0; j < 8; j++)
#pragma unroll
                    for (int rg = 0; rg < 4; rg++) {
                        float p = __expf(sc[qs][j][rg] - mrun[qs][rg]);
                        tsum[rg] += p;
                        const int prow = l4 * 4 + rg;
                        Pl[wid][prow * 128 + ((j * 16 + l15) ^ ((prow & 7) << 3))] = f2bf(p);
                    }
#pragma unroll
                for (int d = 1; d < 16; d <<= 1)
#pragma unroll
                    for (int rg = 0; rg < 4; rg++) tsum[rg] += __shfl_xor(tsum[rg], d);
#pragma unroll
                for (int rg = 0; rg < 4; rg++) lrun[qs][rg] += tsum[rg];

                // ---- O += P V ----
#pragma unroll
                for (int kk = 0; kk < 4; kk++) {
                    bf16x8 ap = *(const bf16x8*)&Pl[wid][l15 * 128 + koff[kk]];
#pragma unroll
                    for (int j6 = 0; j6 < 6; j6++) {
                        bf16x8 bv8 = *(const bf16x8*)&Vt[cur][(j6 * 16 + l15) * 128 + koff[kk]];
                        o[qs][j6] = mfma16(ap, bv8, o[qs][j6]);
                    }
                }
            }
        }

#pragma unroll
        for (int qs = 0; qs < 2; ++qs) {
            float inv[4];
#pragma unroll
            for (int rg = 0; rg < 4; rg++) inv[rg] = 1.f / lrun[qs][rg];
            const size_t orow = (size_t)(qbase + (qt << 8) + (wid << 5) + qs * 16);
#pragma unroll
            for (int j6 = 0; j6 < 6; j6++)
#pragma unroll
                for (int rg = 0; rg < 4; rg++)
                    attn[(orow + l4 * 4 + rg) * 768 + h * 96 + j6 * 16 + l15] =
                        f2bf(o[qs][j6][rg] * inv[rg]);
        }
    }
}

// ---------- LN1 + masked-pool accumulation (bf16 input) ----------
__global__ __launch_bounds__(256) void k_ln_pool(const u16* __restrict__ X,
                                                 const int* __restrict__ vmaskc,
                                                 const int* __restrict__ tmaskc,
                                                 const float* __restrict__ g,
                                                 const float* __restrict__ bb,
                                                 float* __restrict__ pooled,
                                                 int mvisL, int bg0) {
    __shared__ float pool[768];
    const int tid = threadIdx.x, wid = tid >> 6, lane = tid & 63;
    const int row0 = blockIdx.x << 5;
    const bool vis = row0 < mvisL;
    const int* mask = vis ? vmaskc : tmaskc;
    const int mbase = vis ? 0 : mvisL;
    const int bl = vis ? (row0 >> 10) : ((row0 - mvisL) >> 9);
    float* pout = pooled + (vis ? 0 : 12288) + (size_t)(bg0 + bl) * 768;

    float gv[12], bv2[12];
#pragma unroll
    for (int k = 0; k < 12; k++) { gv[k] = g[lane + k * 64]; bv2[k] = bb[lane + k * 64]; }
    float acc[12] = {};
    for (int rr = 0; rr < 8; ++rr) {
        const int row = row0 + (wid << 3) + rr;
        const u16* x = X + (size_t)row * 768;
        float xs[12], sm = 0.f, s2 = 0.f;
#pragma unroll
        for (int k = 0; k < 12; k++) {
            float tv = bf2f(x[lane + k * 64]);
            xs[k] = tv; sm += tv; s2 += tv * tv;
        }
#pragma unroll
        for (int d = 1; d < 64; d <<= 1) { sm += __shfl_xor(sm, d); s2 += __shfl_xor(s2, d); }
        const float mean = sm * (1.f / 768.f);
        const float rstd = rsqrtf(s2 * (1.f / 768.f) - mean * mean + 1e-5f);
        const float mv = (float)mask[row - mbase];
#pragma unroll
        for (int k = 0; k < 12; k++) acc[k] += ((xs[k] - mean) * rstd * gv[k] + bv2[k]) * mv;
    }
    pool[tid] = 0.f; pool[tid + 256] = 0.f; pool[tid + 512] = 0.f;
    __syncthreads();
#pragma unroll
    for (int k = 0; k < 12; k++) atomicAdd(&pool[lane + k * 64], acc[k]);
    __syncthreads();
    atomicAdd(&pout[tid], pool[tid]);
    atomicAdd(&pout[tid + 256], pool[tid + 256]);
    atomicAdd(&pout[tid + 512], pool[tid + 512]);
}

// ---------- final ----------
__device__ __forceinline__ float blk_sum(float v, volatile float* tmp) {
#pragma unroll
    for (int d = 1; d < 64; d <<= 1) v += __shfl_xor(v, d);
    __syncthreads();
    if ((threadIdx.x & 63) == 0) tmp[threadIdx.x >> 6] = v;
    __syncthreads();
    return tmp[0] + tmp[1] + tmp[2] + tmp[3];
}

__global__ __launch_bounds__(256) void k_final(const float* __restrict__ pooled,
                                               const int* __restrict__ vmask,
                                               const int* __restrict__ tmask,
                                               const float* __restrict__ Wf,
                                               const float* __restrict__ bfv,
                                               const float* __restrict__ g2,
                                               const float* __restrict__ b2,
                                               float* __restrict__ out) {
    __shared__ float sh[1536];
    __shared__ float red[4];
    const int b = blockIdx.x, tid = threadIdx.x;
    float cv = 0.f, ct = 0.f;
    for (int i = tid; i < 1024; i += 256) cv += (float)vmask[(b << 10) + i];
    for (int i = tid; i < 512; i += 256) ct += (float)tmask[(b << 9) + i];
    cv = blk_sum(cv, red);
    ct = blk_sum(ct, red);
    const float iv = 1.f / cv, itv = 1.f / ct;
#pragma unroll
    for (int k = 0; k < 3; k++) {
        int j = tid + (k << 8);
        sh[j] = pooled[b * 768 + j] * iv;
        sh[768 + j] = pooled[12288 + b * 768 + j] * itv;
    }
    __syncthreads();
    float f0 = bfv[tid], f1 = bfv[tid + 256], f2 = bfv[tid + 512];
    for (int i = 0; i < 1536; i++) {
        const float pv = sh[i];
        const float* w = Wf + (size_t)i * 768;
        f0 += pv * w[tid];
        f1 += pv * w[tid + 256];
        f2 += pv * w[tid + 512];
    }
    float sm = blk_sum(f0 + f1 + f2, red);
    float s2 = blk_sum(f0 * f0 + f1 * f1 + f2 * f2, red);
    const float mean = sm * (1.f / 768.f);
    const float rstd = rsqrtf(s2 * (1.f / 768.f) - mean * mean + 1e-5f);
    out[b * 768 + tid] = (f0 - mean) * rstd * g2[tid] + b2[tid];
    out[b * 768 + tid + 256] = (f1 - mean) * rstd * g2[tid + 256] + b2[tid + 256];
    out[b * 768 + tid + 512] = (f2 - mean) * rstd * g2[tid + 512] + b2[tid + 512];
}

// ---------- host ----------
extern "C" void kernel_launch(void* const* d_in, const int* in_sizes, int n_in,
                              void* d_out, int out_size, void* d_ws, size_t ws_size,
                              hipStream_t stream) {
    (void)in_sizes; (void)n_in; (void)out_size;
    const float* vf = (const float*)d_in[0];
    const float* tf = (const float*)d_in[1];
    const int* vmask = (const int*)d_in[2];
    const int* tmask = (const int*)d_in[3];
    const float* Wq = (const float*)d_in[4];
    const float* bq = (const float*)d_in[5];
    const float* Wk = (const float*)d_in[6];
    const float* bk = (const float*)d_in[7];
    const float* Wv = (const float*)d_in[8];
    const float* bv = (const float*)d_in[9];
    const float* Wo = (const float*)d_in[10];
    const float* bo = (const float*)d_in[11];
    const float* g1 = (const float*)d_in[12];
    const float* b1 = (const float*)d_in[13];
    const float* Wf = (const float*)d_in[14];
    const float* bfv = (const float*)d_in[15];
    const float* g2 = (const float*)d_in[16];
    const float* b2 = (const float*)d_in[17];
    float* outp = (float*)d_out;

    // footprint = 4,826,112 + CH * (2,359,296 X + 7,077,888 QKV + 2,359,296 VtG)
    int CH = 16;
    while (CH > 1 && 4826112ull + (size_t)CH * 11796480ull > ws_size) CH >>= 1;
    const int NC = 16 / CH;
    const int Rtot = CH * 1536;

    char* ws = (char*)d_ws;
    u16*   wsW      = (u16*)(ws);
    u16*   wsWo     = (u16*)(ws + 3538944);
    float* wsBqkv   = (float*)(ws + 4718592);
    float* wsPooled = (float*)(ws + 4727808);
    u16*   wsX      = (u16*)(ws + 4826112);                 // [R][768] bf16 (reused: attn out)
    char*  qkvBase  = ws + 4826112 + (size_t)CH * 2359296;
    u16*   wsQKV    = (u16*)qkvBase;                         // [R][2304] bf16 (reused: Oproj bf16)
    u16*   wsOproj  = (u16*)qkvBase;
    u16*   wsVtG    = (u16*)(qkvBase + (size_t)CH * 7077888);// [768][R] bf16
    u16*   wsAttn   = wsX;

    k_transpose<<<dim3(144), dim3(256), 0, stream>>>(Wq, wsW, 768, 768);
    k_transpose<<<dim3(144), dim3(256), 0, stream>>>(Wk, wsW + 589824, 768, 768);
    k_transpose<<<dim3(144), dim3(256), 0, stream>>>(Wv, wsW + 1179648, 768, 768);
    k_transpose<<<dim3(144), dim3(256), 0, stream>>>(Wo, wsWo, 768, 768);
    k_bias<<<dim3(9), dim3(256), 0, stream>>>(bq, bk, bv, wsBqkv);
    k_zero<<<dim3(96), dim3(256), 0, stream>>>(wsPooled);

    for (int c = 0; c < NC; ++c) {
        const float* vfc = vf + (size_t)c * CH * 1024 * 768;
        const float* tfc = tf + (size_t)c * CH * 512 * 768;
        const int* vmc = vmask + c * CH * 1024;
        const int* tmc = tmask + c * CH * 512;

        k_cvt_x<<<dim3(CH * 1152), dim3(256), 0, stream>>>(vfc, tfc, wsX, CH * 196608);

        // QKV GEMM; V third written transposed directly into VtG
        k_gemm<true, false, true><<<dim3(CH * 216), dim3(256), 0, stream>>>(
            wsX, wsW, wsBqkv, nullptr, nullptr, (void*)wsQKV, 2304, 768, 0, wsVtG, Rtot);

        k_attn<<<dim3(CH * 16), dim3(512), 0, stream>>>(
            wsQKV, wsVtG, vmc, tmc, wsAttn, CH, Rtot);

        // O-proj + bias + residual, bf16 out
        k_gemm<true, true, false><<<dim3(CH * 72), dim3(256), 0, stream>>>(
            wsAttn, wsWo, bo, vfc, tfc, (void*)wsOproj, 768, 768, CH * 1024, nullptr, 0);

        k_ln_pool<<<dim3(CH * 48), dim3(256), 0, stream>>>(
            wsOproj, vmc, tmc, g1, b1, wsPooled, CH * 1024, c * CH);
    }

    k_final<<<dim3(16), dim3(256), 0, stream>>>(wsPooled, vmask, tmask, Wf, bfv, g2, b2, outp);
}

// Round 15
// 433.898 us; speedup vs baseline: 1.0585x; 1.0483x over previous
//
#include <hip/hip_runtime.h>

typedef __bf16 bf16x8 __attribute__((ext_vector_type(8)));
typedef __bf16 bf16x4v __attribute__((ext_vector_type(4)));
typedef short s16x4 __attribute__((ext_vector_type(4)));
typedef float f32x4 __attribute__((ext_vector_type(4)));
typedef unsigned short u16;
typedef unsigned int u32;
typedef u16 u16x8 __attribute__((ext_vector_type(8)));
typedef u16 u16x4 __attribute__((ext_vector_type(4)));

// B=16, SV=1024, ST=512, D=768, H=8, DH=96. Chunked over CH batches,
// R = CH*1536 rows (CH*1024 visual then CH*512 text).

__device__ __forceinline__ u16 f2bf(float f) {
    u32 u = __builtin_bit_cast(u32, f);
    u32 r = u + 0x7FFFu + ((u >> 16) & 1u);
    return (u16)(r >> 16);
}

__device__ __forceinline__ float bf2f(u16 b) {
    u32 u = ((u32)b) << 16;
    return __builtin_bit_cast(float, u);
}

__device__ __forceinline__ f32x4 mfma16(bf16x8 a, bf16x8 b, f32x4 c) {
    return __builtin_amdgcn_mfma_f32_16x16x32_bf16(a, b, c, 0, 0, 0);
}

// 16x16x16 bf16 MFMA (A/B = 4 bf16/lane, k = (lane>>4)*4+e)
__device__ __forceinline__ f32x4 mfma16k16(bf16x4v a, bf16x4v b, f32x4 c) {
#if __has_builtin(__builtin_amdgcn_mfma_f32_16x16x16_bf16)
    return __builtin_amdgcn_mfma_f32_16x16x16_bf16(a, b, c, 0, 0, 0);
#elif __has_builtin(__builtin_amdgcn_mfma_f32_16x16x16bf16_1k)
    return __builtin_amdgcn_mfma_f32_16x16x16bf16_1k(
        __builtin_bit_cast(s16x4, a), __builtin_bit_cast(s16x4, b), c, 0, 0, 0);
#else
    f32x4 d;
    asm volatile("v_mfma_f32_16x16x16_bf16 %0, %1, %2, %3"
                 : "=v"(d) : "v"(a), "v"(b), "v"(c));
    return d;
#endif
}

#define GLOAD_LDS16(g, l) __builtin_amdgcn_global_load_lds( \
    (__attribute__((address_space(1))) void*)(g), \
    (__attribute__((address_space(3))) void*)(l), 16, 0, 0)

// ---------- prep kernels ----------

__global__ __launch_bounds__(256) void k_cvt_x(const float* __restrict__ vf,
                                               const float* __restrict__ tf,
                                               u16* __restrict__ X, int nvis4) {
    int i = blockIdx.x * 256 + threadIdx.x;
    f32x4 v = (i < nvis4) ? ((const f32x4*)vf)[i] : ((const f32x4*)tf)[i - nvis4];
    u16x4 o = { f2bf(v[0]), f2bf(v[1]), f2bf(v[2]), f2bf(v[3]) };
    ((u16x4*)X)[i] = o;
}

// src f32 [K0][N0] -> dst bf16 [N0][K0]   (64x64 LDS tiles)
__global__ __launch_bounds__(256) void k_transpose(const float* __restrict__ src,
                                                   u16* __restrict__ dst,
                                                   int K0, int N0) {
    __shared__ float t[64][65];
    int ntx = N0 >> 6;
    int k0 = (blockIdx.x / ntx) << 6, n0 = (blockIdx.x % ntx) << 6;
    int c = threadIdx.x & 63, rr = threadIdx.x >> 6;
#pragma unroll
    for (int q = 0; q < 16; q++) {
        int r = q * 4 + rr;
        t[r][c] = src[(size_t)(k0 + r) * N0 + n0 + c];
    }
    __syncthreads();
#pragma unroll
    for (int q = 0; q < 16; q++) {
        int r = q * 4 + rr;
        dst[(size_t)(n0 + r) * K0 + k0 + c] = f2bf(t[c][r]);
    }
}

__global__ __launch_bounds__(256) void k_bias(const float* __restrict__ bq,
                                              const float* __restrict__ bk,
                                              const float* __restrict__ bv,
                                              float* __restrict__ bqkv) {
    int n = blockIdx.x * 256 + threadIdx.x;
    if (n < 2304) {
        const float* s = (n < 768) ? bq : ((n < 1536) ? bk : bv);
        int r = (n < 768) ? n : ((n < 1536) ? n - 768 : n - 1536);
        bqkv[n] = s[r];
    }
}

__global__ __launch_bounds__(256) void k_zero(float* __restrict__ p) {
    p[blockIdx.x * 256 + threadIdx.x] = 0.f;
}

// ---------- GEMM: C[R][N] = A[R][K] * Bt[N][K]^T + bias (+residual) ----------
// XCD-chunked blockIdx swizzle; 2-phase pipeline (dbuf LDS, one barrier/step).
template <bool OUT_BF16, bool ADD_RES, bool SPLIT_VT>
__global__ __launch_bounds__(256) void k_gemm(const u16* __restrict__ A,
                                              const u16* __restrict__ Bt,
                                              const float* __restrict__ bias,
                                              const float* __restrict__ resA,
                                              const float* __restrict__ resB,
                                              void* __restrict__ Cout,
                                              int Ndim, int Kdim, int mvisL,
                                              u16* __restrict__ VtGp, int Rtot) {
    __shared__ alignas(16) u16 sA[2][128 * 32];
    __shared__ alignas(16) u16 sB[2][128 * 32];
    const int tid = threadIdx.x, wid = tid >> 6, lane = tid & 63;
    const int nwg = gridDim.x;
    const int wg = (blockIdx.x & 7) * (nwg >> 3) + (blockIdx.x >> 3);
    const int ntiles = Ndim >> 7;
    const int mt = wg / ntiles, nt = wg - mt * ntiles;
    const int m0 = mt << 7, n0 = nt << 7;
    const int wm = wid >> 1, wn = wid & 1;
    f32x4 acc[4][4] = {};

    const int r0 = tid >> 2, p0 = tid & 3;
    const int r1 = 64 + r0;
    const u16* ga0 = A + (size_t)(m0 + r0) * Kdim + p0 * 8;
    const u16* ga1 = A + (size_t)(m0 + r1) * Kdim + p0 * 8;
    const u16* gb0 = Bt + (size_t)(n0 + r0) * Kdim + p0 * 8;
    const u16* gb1 = Bt + (size_t)(n0 + r1) * Kdim + p0 * 8;
    const int loff0 = wid * 512;
    const int loff1 = 2048 + wid * 512;

    const int arow = (wm << 6) + (lane & 15);
    const int brow = (wn << 6) + (lane & 15);
    const int kg = (lane >> 4) * 8;

    auto stage = [&](int kt, int pb) {
        GLOAD_LDS16(ga0 + kt, &sA[pb][loff0]);
        GLOAD_LDS16(ga1 + kt, &sA[pb][loff1]);
        GLOAD_LDS16(gb0 + kt, &sB[pb][loff0]);
        GLOAD_LDS16(gb1 + kt, &sB[pb][loff1]);
    };

    const int niter = Kdim >> 5;
    stage(0, 0);
    for (int it = 0; it < niter; ++it) {
        const int cur = it & 1;
        __syncthreads();
        if (it + 1 < niter) stage((it + 1) << 5, cur ^ 1);
        bf16x8 av[4], bw[4];
#pragma unroll
        for (int i = 0; i < 4; i++) av[i] = *(const bf16x8*)&sA[cur][(arow + i * 16) * 32 + kg];
#pragma unroll
        for (int j = 0; j < 4; j++) bw[j] = *(const bf16x8*)&sB[cur][(brow + j * 16) * 32 + kg];
#pragma unroll
        for (int i = 0; i < 4; i++)
#pragma unroll
            for (int j = 0; j < 4; j++) acc[i][j] = mfma16(av[i], bw[j], acc[i][j]);
    }

    const int col0 = n0 + (wn << 6) + (lane & 15);
    const int rowb = m0 + (wm << 6) + ((lane >> 4) << 2);
    float bvals[4];
#pragma unroll
    for (int j = 0; j < 4; j++) bvals[j] = bias[col0 + j * 16];

    if constexpr (SPLIT_VT) {
        if (n0 >= 1536) {
            const int vcol0 = col0 - 1536;
#pragma unroll
            for (int i = 0; i < 4; i++) {
#pragma unroll
                for (int j = 0; j < 4; j++) {
                    u16x4 o4;
#pragma unroll
                    for (int rg = 0; rg < 4; rg++) o4[rg] = f2bf(acc[i][j][rg] + bvals[j]);
                    *(u16x4*)&VtGp[(size_t)(vcol0 + j * 16) * Rtot + rowb + i * 16] = o4;
                }
            }
            return;
        }
    }

#pragma unroll
    for (int i = 0; i < 4; i++) {
#pragma unroll
        for (int rg = 0; rg < 4; rg++) {
            const int row = rowb + i * 16 + rg;
            const float* rp = nullptr;
            if constexpr (ADD_RES)
                rp = (row < mvisL) ? resA + (size_t)row * 768
                                   : resB + (size_t)(row - mvisL) * 768;
#pragma unroll
            for (int j = 0; j < 4; j++) {
                const int col = col0 + j * 16;
                float v = acc[i][j][rg] + bvals[j];
                if constexpr (ADD_RES) v += rp[col];
                if constexpr (OUT_BF16)
                    ((u16*)Cout)[(size_t)row * Ndim + col] = f2bf(v);
                else
                    ((float*)Cout)[(size_t)row * Ndim + col] = v;
            }
        }
    }
}

// ---------- fused cross-attention ----------
// R7 sync structure (one barrier/step, K+V dbuf, stage(s+1) after barrier,
// serpentine). NEW: swapped QK^T (S^T = mfma(K,Q)) so each lane holds P rows
// for q=lane&15 with k in (j,rg,l4). Softmax: in-lane reduce + 2 shfl_xor.
// PV: P quads ARE the 16x16x16 A-fragment -> no P LDS round-trip at all.
__global__ __launch_bounds__(512) void k_attn(const u16* __restrict__ qkv,
                                              const u16* __restrict__ VtG,
                                              const int* __restrict__ vmaskc,
                                              const int* __restrict__ tmaskc,
                                              u16* __restrict__ attn, int CHn, int Rtot) {
    __shared__ alignas(16) u16 Kl[2][128 * 128];   // 64 KB
    __shared__ alignas(16) u16 Vt[2][96 * 128];    // 48 KB
    __shared__ float mk[2][128];

    const int bx = blockIdx.x;
    int b, h, qbase, kbase, nqt, ntl;
    const int* mask;
    const int vcap = CHn * 8;
    if (bx < vcap) {   // visual queries attend to text: 4 passes x 256 rows
        b = bx >> 3; h = bx & 7;
        qbase = b << 10; kbase = (CHn << 10) + (b << 9);
        mask = tmaskc + (b << 9); nqt = 4; ntl = 2;   // ntile=4 (Sk=512)
    } else {           // text queries attend to visual: 2 passes x 256 rows
        const int bx2 = bx - vcap;
        b = bx2 >> 3; h = bx2 & 7;
        qbase = (CHn << 10) + (b << 9); kbase = b << 10;
        mask = vmaskc + (b << 10); nqt = 2; ntl = 3;  // ntile=8 (Sk=1024)
    }
    const int ntile = 1 << ntl;
    const int nsteps = nqt << ntl;
    const int tid = threadIdx.x, wid = tid >> 6, lane = tid & 63;
    const int l15 = lane & 15, l4 = lane >> 4;
    const float scale = 0.10206207261596577f;  // 1/sqrt(96)

    int koff[3];
#pragma unroll
    for (int kk = 0; kk < 3; kk++) koff[kk] = ((kk * 4 + l4) ^ (l15 & 7)) << 3;

    auto kt_of = [&](int s) {
        const int qt = s >> ntl, ktr = s & (ntile - 1);
        return (qt & 1) ? (ntile - 1 - ktr) : ktr;   // serpentine
    };
    auto stage = [&](int kt, int pb) {
#pragma unroll
        for (int it = 0; it < 4; ++it) {             // K tile: 2048 16B chunks
            const int cb = it * 512 + (wid << 6);
            const int c = cb + lane;
            const int r = c >> 4, s8 = c & 15;
            const int k8 = s8 ^ (r & 7);
            const u16* src = qkv + (size_t)(kbase + (kt << 7) + r) * 2304 + 768 + h * 96
                             + (k8 < 12 ? k8 * 8 : 0);
            GLOAD_LDS16(src, &Kl[pb][(size_t)cb * 8]);
        }
#pragma unroll
        for (int it = 0; it < 3; ++it) {             // V tile: 1536 16B chunks
            const int cb = it * 512 + (wid << 6);
            const int c = cb + lane;
            const int d = c >> 4, s8 = c & 15;
            const int k8 = s8 ^ (d & 7);
            const u16* src = VtG + (size_t)(h * 96 + d) * Rtot + kbase + (kt << 7) + k8 * 8;
            GLOAD_LDS16(src, &Vt[pb][(size_t)cb * 8]);
        }
        if (tid < 128) mk[pb][tid] = mask[(kt << 7) + tid] ? 0.f : -1e30f;
    };

    stage(kt_of(0), 0);
    int s = 0;
    for (int qt = 0; qt < nqt; ++qt) {
        bf16x8 aq[2][3];
#pragma unroll
        for (int qs = 0; qs < 2; ++qs) {
            const int qr = qbase + (qt << 8) + (wid << 5) + qs * 16 + l15;
#pragma unroll
            for (int kk = 0; kk < 3; kk++) {
                bf16x8 tq = *(const bf16x8*)&qkv[(size_t)qr * 2304 + h * 96 + kk * 32 + l4 * 8];
#pragma unroll
                for (int e = 0; e < 8; e++) tq[e] = (__bf16)((float)tq[e] * scale);
                aq[qs][kk] = tq;
            }
        }
        f32x4 o[2][6] = {};
        float mrunS[2] = {-1e30f, -1e30f};
        float lrunS[2] = {0.f, 0.f};

        for (int ktr = 0; ktr < ntile; ++ktr, ++s) {
            const int cur = s & 1;
            __syncthreads();                      // publish stage(cur); reads of cur^1 done
            if (s + 1 < nsteps) stage(kt_of(s + 1), cur ^ 1);

            // ---- S^T = K Q^T, j-outer (K fragments shared by both q-sets) ----
            // lane: col q = l15, row k = j*16 + l4*4 + rg
            f32x4 sc[2][8];
#pragma unroll
            for (int j = 0; j < 8; j++) {
                const int rbase = (j * 16 + l15) * 128;
                bf16x8 bk[3];
#pragma unroll
                for (int kk = 0; kk < 3; kk++)
                    bk[kk] = *(const bf16x8*)&Kl[cur][rbase + koff[kk]];
#pragma unroll
                for (int qs = 0; qs < 2; ++qs) {
                    f32x4 cj = {0.f, 0.f, 0.f, 0.f};
#pragma unroll
                    for (int kk = 0; kk < 3; kk++) cj = mfma16(bk[kk], aq[qs][kk], cj);
                    sc[qs][j] = cj;
                }
            }

            bf16x4v pb[2][8];
#pragma unroll
            for (int qs = 0; qs < 2; ++qs) {
                // ---- additive mask + max over k (in-lane + l4 via shfl) ----
                float tm = -1e30f;
#pragma unroll
                for (int j = 0; j < 8; j++) {
                    f32x4 m4 = *(const f32x4*)&mk[cur][j * 16 + (l4 << 2)];
#pragma unroll
                    for (int rg = 0; rg < 4; rg++) {
                        float v = sc[qs][j][rg] + m4[rg];
                        sc[qs][j][rg] = v;
                        tm = fmaxf(tm, v);
                    }
                }
                tm = fmaxf(tm, __shfl_xor(tm, 16));
                tm = fmaxf(tm, __shfl_xor(tm, 32));
                // ---- defer-max rescale (THR=8); o's rg-index is q=l4*4+rg ----
                const int need = (tm > mrunS[qs] + 8.f) ? 1 : 0;
                if (__any(need)) {
                    float mn = fmaxf(mrunS[qs], tm);
                    float corrS = __expf(mrunS[qs] - mn);
                    mrunS[qs] = mn;
                    lrunS[qs] *= corrS;
                    float cr[4];
#pragma unroll
                    for (int rg = 0; rg < 4; rg++) cr[rg] = __shfl(corrS, (l4 << 2) + rg);
#pragma unroll
                    for (int j6 = 0; j6 < 6; j6++)
#pragma unroll
                        for (int rg = 0; rg < 4; rg++) o[qs][j6][rg] *= cr[rg];
                }
                // ---- P = exp(S - m): stays in registers as PV A-fragments ----
                float ts = 0.f;
#pragma unroll
                for (int j = 0; j < 8; j++) {
                    bf16x4v pq;
#pragma unroll
                    for (int rg = 0; rg < 4; rg++) {
                        float p = __expf(sc[qs][j][rg] - mrunS[qs]);
                        ts += p;
                        pq[rg] = (__bf16)p;
                    }
                    pb[qs][j] = pq;
                }
                ts += __shfl_xor(ts, 16);
                ts += __shfl_xor(ts, 32);
                lrunS[qs] += ts;
            }

            // ---- O += P V via 16x16x16 MFMA; V b64 reads shared by both q-sets ----
#pragma unroll
            for (int j = 0; j < 8; j++) {
                const int slotb = 2 * j + (l4 >> 1);
                const int intra = (l4 & 1) << 2;
#pragma unroll
                for (int j6 = 0; j6 < 6; j6++) {
                    const int d = j6 * 16 + l15;
                    bf16x4v bv = *(const bf16x4v*)&Vt[cur][d * 128 +
                                     ((slotb ^ (l15 & 7)) << 3) + intra];
                    o[0][j6] = mfma16k16(pb[0][j], bv, o[0][j6]);
                    o[1][j6] = mfma16k16(pb[1][j], bv, o[1][j6]);
                }
            }
        }

#pragma unroll
        for (int qs = 0; qs < 2; ++qs) {
            const float invS = 1.f / lrunS[qs];
            float inv[4];
#pragma unroll
            for (int rg = 0; rg < 4; rg++) inv[rg] = __shfl(invS, (l4 << 2) + rg);
            const size_t orow = (size_t)(qbase + (qt << 8) + (wid << 5) + qs * 16);
#pragma unroll
            for (int j6 = 0; j6 < 6; j6++)
#pragma unroll
                for (int rg = 0; rg < 4; rg++)
                    attn[(orow + l4 * 4 + rg) * 768 + h * 96 + j6 * 16 + l15] =
                        f2bf(o[qs][j6][rg] * inv[rg]);
        }
    }
}

// ---------- LN1 + masked-pool accumulation (bf16 input) ----------
__global__ __launch_bounds__(256) void k_ln_pool(const u16* __restrict__ X,
                                                 const int* __restrict__ vmaskc,
                                                 const int* __restrict__ tmaskc,
                                                 const float* __restrict__ g,
                                                 const float* __restrict__ bb,
                                                 float* __restrict__ pooled,
                                                 int mvisL, int bg0) {
    __shared__ float pool[768];
    const int tid = threadIdx.x, wid = tid >> 6, lane = tid & 63;
    const int row0 = blockIdx.x << 5;
    const bool vis = row0 < mvisL;
    const int* mask = vis ? vmaskc : tmaskc;
    const int mbase = vis ? 0 : mvisL;
    const int bl = vis ? (row0 >> 10) : ((row0 - mvisL) >> 9);
    float* pout = pooled + (vis ? 0 : 12288) + (size_t)(bg0 + bl) * 768;

    float gv[12], bv2[12];
#pragma unroll
    for (int k = 0; k < 12; k++) { gv[k] = g[lane + k * 64]; bv2[k] = bb[lane + k * 64]; }
    float acc[12] = {};
    for (int rr = 0; rr < 8; ++rr) {
        const int row = row0 + (wid << 3) + rr;
        const u16* x = X + (size_t)row * 768;
        float xs[12], sm = 0.f, s2 = 0.f;
#pragma unroll
        for (int k = 0; k < 12; k++) {
            float tv = bf2f(x[lane + k * 64]);
            xs[k] = tv; sm += tv; s2 += tv * tv;
        }
#pragma unroll
        for (int d = 1; d < 64; d <<= 1) { sm += __shfl_xor(sm, d); s2 += __shfl_xor(s2, d); }
        const float mean = sm * (1.f / 768.f);
        const float rstd = rsqrtf(s2 * (1.f / 768.f) - mean * mean + 1e-5f);
        const float mv = (float)mask[row - mbase];
#pragma unroll
        for (int k = 0; k < 12; k++) acc[k] += ((xs[k] - mean) * rstd * gv[k] + bv2[k]) * mv;
    }
    pool[tid] = 0.f; pool[tid + 256] = 0.f; pool[tid + 512] = 0.f;
    __syncthreads();
#pragma unroll
    for (int k = 0; k < 12; k++) atomicAdd(&pool[lane + k * 64], acc[k]);
    __syncthreads();
    atomicAdd(&pout[tid], pool[tid]);
    atomicAdd(&pout[tid + 256], pool[tid + 256]);
    atomicAdd(&pout[tid + 512], pool[tid + 512]);
}

// ---------- final ----------
__device__ __forceinline__ float blk_sum(float v, volatile float* tmp) {
#pragma unroll
    for (int d = 1; d < 64; d <<= 1) v += __shfl_xor(v, d);
    __syncthreads();
    if ((threadIdx.x & 63) == 0) tmp[threadIdx.x >> 6] = v;
    __syncthreads();
    return tmp[0] + tmp[1] + tmp[2] + tmp[3];
}

__global__ __launch_bounds__(256) void k_final(const float* __restrict__ pooled,
                                               const int* __restrict__ vmask,
                                               const int* __restrict__ tmask,
                                               const float* __restrict__ Wf,
                                               const float* __restrict__ bfv,
                                               const float* __restrict__ g2,
                                               const float* __restrict__ b2,
                                               float* __restrict__ out) {
    __shared__ float sh[1536];
    __shared__ float red[4];
    const int b = blockIdx.x, tid = threadIdx.x;
    float cv = 0.f, ct = 0.f;
    for (int i = tid; i < 1024; i += 256) cv += (float)vmask[(b << 10) + i];
    for (int i = tid; i < 512; i += 256) ct += (float)tmask[(b << 9) + i];
    cv = blk_sum(cv, red);
    ct = blk_sum(ct, red);
    const float iv = 1.f / cv, itv = 1.f / ct;
#pragma unroll
    for (int k = 0; k < 3; k++) {
        int j = tid + (k << 8);
        sh[j] = pooled[b * 768 + j] * iv;
        sh[768 + j] = pooled[12288 + b * 768 + j] * itv;
    }
    __syncthreads();
    float f0 = bfv[tid], f1 = bfv[tid + 256], f2 = bfv[tid + 512];
    for (int i = 0; i < 1536; i++) {
        const float pv = sh[i];
        const float* w = Wf + (size_t)i * 768;
        f0 += pv * w[tid];
        f1 += pv * w[tid + 256];
        f2 += pv * w[tid + 512];
    }
    float sm = blk_sum(f0 + f1 + f2, red);
    float s2 = blk_sum(f0 * f0 + f1 * f1 + f2 * f2, red);
    const float mean = sm * (1.f / 768.f);
    const float rstd = rsqrtf(s2 * (1.f / 768.f) - mean * mean + 1e-5f);
    out[b * 768 + tid] = (f0 - mean) * rstd * g2[tid] + b2[tid];
    out[b * 768 + tid + 256] = (f1 - mean) * rstd * g2[tid + 256] + b2[tid + 256];
    out[b * 768 + tid + 512] = (f2 - mean) * rstd * g2[tid + 512] + b2[tid + 512];
}

// ---------- host ----------
extern "C" void kernel_launch(void* const* d_in, const int* in_sizes, int n_in,
                              void* d_out, int out_size, void* d_ws, size_t ws_size,
                              hipStream_t stream) {
    (void)in_sizes; (void)n_in; (void)out_size;
    const float* vf = (const float*)d_in[0];
    const float* tf = (const float*)d_in[1];
    const int* vmask = (const int*)d_in[2];
    const int* tmask = (const int*)d_in[3];
    const float* Wq = (const float*)d_in[4];
    const float* bq = (const float*)d_in[5];
    const float* Wk = (const float*)d_in[6];
    const float* bk = (const float*)d_in[7];
    const float* Wv = (const float*)d_in[8];
    const float* bv = (const float*)d_in[9];
    const float* Wo = (const float*)d_in[10];
    const float* bo = (const float*)d_in[11];
    const float* g1 = (const float*)d_in[12];
    const float* b1 = (const float*)d_in[13];
    const float* Wf = (const float*)d_in[14];
    const float* bfv = (const float*)d_in[15];
    const float* g2 = (const float*)d_in[16];
    const float* b2 = (const float*)d_in[17];
    float* outp = (float*)d_out;

    // footprint = 4,826,112 + CH * (2,359,296 X + 7,077,888 QKV + 2,359,296 VtG)
    int CH = 16;
    while (CH > 1 && 4826112ull + (size_t)CH * 11796480ull > ws_size) CH >>= 1;
    const int NC = 16 / CH;
    const int Rtot = CH * 1536;

    char* ws = (char*)d_ws;
    u16*   wsW      = (u16*)(ws);
    u16*   wsWo     = (u16*)(ws + 3538944);
    float* wsBqkv   = (float*)(ws + 4718592);
    float* wsPooled = (float*)(ws + 4727808);
    u16*   wsX      = (u16*)(ws + 4826112);                 // [R][768] bf16 (reused: attn out)
    char*  qkvBase  = ws + 4826112 + (size_t)CH * 2359296;
    u16*   wsQKV    = (u16*)qkvBase;                         // [R][2304] bf16 (reused: Oproj bf16)
    u16*   wsOproj  = (u16*)qkvBase;
    u16*   wsVtG    = (u16*)(qkvBase + (size_t)CH * 7077888);// [768][R] bf16
    u16*   wsAttn   = wsX;

    k_transpose<<<dim3(144), dim3(256), 0, stream>>>(Wq, wsW, 768, 768);
    k_transpose<<<dim3(144), dim3(256), 0, stream>>>(Wk, wsW + 589824, 768, 768);
    k_transpose<<<dim3(144), dim3(256), 0, stream>>>(Wv, wsW + 1179648, 768, 768);
    k_transpose<<<dim3(144), dim3(256), 0, stream>>>(Wo, wsWo, 768, 768);
    k_bias<<<dim3(9), dim3(256), 0, stream>>>(bq, bk, bv, wsBqkv);
    k_zero<<<dim3(96), dim3(256), 0, stream>>>(wsPooled);

    for (int c = 0; c < NC; ++c) {
        const float* vfc = vf + (size_t)c * CH * 1024 * 768;
        const float* tfc = tf + (size_t)c * CH * 512 * 768;
        const int* vmc = vmask + c * CH * 1024;
        const int* tmc = tmask + c * CH * 512;

        k_cvt_x<<<dim3(CH * 1152), dim3(256), 0, stream>>>(vfc, tfc, wsX, CH * 196608);

        // QKV GEMM; V third written transposed directly into VtG
        k_gemm<true, false, true><<<dim3(CH * 216), dim3(256), 0, stream>>>(
            wsX, wsW, wsBqkv, nullptr, nullptr, (void*)wsQKV, 2304, 768, 0, wsVtG, Rtot);

        k_attn<<<dim3(CH * 16), dim3(512), 0, stream>>>(
            wsQKV, wsVtG, vmc, tmc, wsAttn, CH, Rtot);

        // O-proj + bias + residual, bf16 out
        k_gemm<true, true, false><<<dim3(CH * 72), dim3(256), 0, stream>>>(
            wsAttn, wsWo, bo, vfc, tfc, (void*)wsOproj, 768, 768, CH * 1024, nullptr, 0);

        k_ln_pool<<<dim3(CH * 48), dim3(256), 0, stream>>>(
            wsOproj, vmc, tmc, g1, b1, wsPooled, CH * 1024, c * CH);
    }

    k_final<<<dim3(16), dim3(256), 0, stream>>>(wsPooled, vmask, tmask, Wf, bfv, g2, b2, outp);
}

// Round 16
// 380.172 us; speedup vs baseline: 1.2081x; 1.1413x over previous
//
#include <hip/hip_runtime.h>

typedef __bf16 bf16x8 __attribute__((ext_vector_type(8)));
typedef __bf16 bf16x4v __attribute__((ext_vector_type(4)));
typedef short s16x4 __attribute__((ext_vector_type(4)));
typedef float f32x4 __attribute__((ext_vector_type(4)));
typedef unsigned short u16;
typedef unsigned int u32;
typedef u16 u16x8 __attribute__((ext_vector_type(8)));
typedef u16 u16x4 __attribute__((ext_vector_type(4)));

// B=16, SV=1024, ST=512, D=768, H=8, DH=96. Chunked over CH batches,
// R = CH*1536 rows (CH*1024 visual then CH*512 text).

__device__ __forceinline__ u16 f2bf(float f) {
    u32 u = __builtin_bit_cast(u32, f);
    u32 r = u + 0x7FFFu + ((u >> 16) & 1u);
    return (u16)(r >> 16);
}

__device__ __forceinline__ float bf2f(u16 b) {
    u32 u = ((u32)b) << 16;
    return __builtin_bit_cast(float, u);
}

__device__ __forceinline__ f32x4 mfma16(bf16x8 a, bf16x8 b, f32x4 c) {
    return __builtin_amdgcn_mfma_f32_16x16x32_bf16(a, b, c, 0, 0, 0);
}

// 16x16x16 bf16 MFMA (A/B = 4 bf16/lane, k = (lane>>4)*4+e)
__device__ __forceinline__ f32x4 mfma16k16(bf16x4v a, bf16x4v b, f32x4 c) {
#if __has_builtin(__builtin_amdgcn_mfma_f32_16x16x16_bf16)
    return __builtin_amdgcn_mfma_f32_16x16x16_bf16(a, b, c, 0, 0, 0);
#elif __has_builtin(__builtin_amdgcn_mfma_f32_16x16x16bf16_1k)
    return __builtin_amdgcn_mfma_f32_16x16x16bf16_1k(
        __builtin_bit_cast(s16x4, a), __builtin_bit_cast(s16x4, b), c, 0, 0, 0);
#else
    f32x4 d;
    asm volatile("v_mfma_f32_16x16x16_bf16 %0, %1, %2, %3"
                 : "=v"(d) : "v"(a), "v"(b), "v"(c));
    return d;
#endif
}

#define GLOAD_LDS16(g, l) __builtin_amdgcn_global_load_lds( \
    (__attribute__((address_space(1))) void*)(g), \
    (__attribute__((address_space(3))) void*)(l), 16, 0, 0)

// ---------- prep kernels ----------

__global__ __launch_bounds__(256) void k_cvt_x(const float* __restrict__ vf,
                                               const float* __restrict__ tf,
                                               u16* __restrict__ X, int nvis4) {
    int i = blockIdx.x * 256 + threadIdx.x;
    f32x4 v = (i < nvis4) ? ((const f32x4*)vf)[i] : ((const f32x4*)tf)[i - nvis4];
    u16x4 o = { f2bf(v[0]), f2bf(v[1]), f2bf(v[2]), f2bf(v[3]) };
    ((u16x4*)X)[i] = o;
}

// src f32 [K0][N0] -> dst bf16 [N0][K0]   (64x64 LDS tiles)
__global__ __launch_bounds__(256) void k_transpose(const float* __restrict__ src,
                                                   u16* __restrict__ dst,
                                                   int K0, int N0) {
    __shared__ float t[64][65];
    int ntx = N0 >> 6;
    int k0 = (blockIdx.x / ntx) << 6, n0 = (blockIdx.x % ntx) << 6;
    int c = threadIdx.x & 63, rr = threadIdx.x >> 6;
#pragma unroll
    for (int q = 0; q < 16; q++) {
        int r = q * 4 + rr;
        t[r][c] = src[(size_t)(k0 + r) * N0 + n0 + c];
    }
    __syncthreads();
#pragma unroll
    for (int q = 0; q < 16; q++) {
        int r = q * 4 + rr;
        dst[(size_t)(n0 + r) * K0 + k0 + c] = f2bf(t[c][r]);
    }
}

__global__ __launch_bounds__(256) void k_bias(const float* __restrict__ bq,
                                              const float* __restrict__ bk,
                                              const float* __restrict__ bv,
                                              float* __restrict__ bqkv) {
    int n = blockIdx.x * 256 + threadIdx.x;
    if (n < 2304) {
        const float* s = (n < 768) ? bq : ((n < 1536) ? bk : bv);
        int r = (n < 768) ? n : ((n < 1536) ? n - 768 : n - 1536);
        bqkv[n] = s[r];
    }
}

__global__ __launch_bounds__(256) void k_zero(float* __restrict__ p) {
    p[blockIdx.x * 256 + threadIdx.x] = 0.f;
}

// ---------- GEMM: C[R][N] = A[R][K] * Bt[N][K]^T + bias (+residual) ----------
// 256x128 tile, BK=32, 8 waves (4m x 2n), 512 threads. Same 2-phase sync as
// R12-R15 (dbuf LDS, ONE __syncthreads per K-step, stage(it+1) after barrier).
// LDS 48KB -> 3 blocks/CU (24 waves) for latency hiding.
// XCD-chunked blockIdx swizzle only when grid % 8 == 0 (bijectivity).
template <bool OUT_BF16, bool ADD_RES, bool SPLIT_VT>
__global__ __launch_bounds__(512) void k_gemm(const u16* __restrict__ A,
                                              const u16* __restrict__ Bt,
                                              const float* __restrict__ bias,
                                              const float* __restrict__ resA,
                                              const float* __restrict__ resB,
                                              void* __restrict__ Cout,
                                              int Ndim, int Kdim, int mvisL,
                                              u16* __restrict__ VtGp, int Rtot) {
    __shared__ alignas(16) u16 sA[2][256 * 32];   // 32 KB
    __shared__ alignas(16) u16 sB[2][128 * 32];   // 16 KB
    const int tid = threadIdx.x, wid = tid >> 6, lane = tid & 63;
    const int nwg = gridDim.x;
    const int wg = (nwg & 7) ? (int)blockIdx.x
                             : ((blockIdx.x & 7) * (nwg >> 3) + (blockIdx.x >> 3));
    const int ntiles = Ndim >> 7;
    const int mt = wg / ntiles, nt = wg - mt * ntiles;
    const int m0 = mt << 8, n0 = nt << 7;
    const int wm = wid >> 1, wn = wid & 1;        // 4m x 2n waves, 64x64 each
    f32x4 acc[4][4] = {};

    // staging: A granules g=tid (rows 0..127) and g=512+tid (rows 128..255);
    // B granules g=tid (rows 0..127). granule -> r=g>>2, chunk p=g&3.
    const int r0 = tid >> 2, p0 = tid & 3;
    const u16* gaA0 = A + (size_t)(m0 + r0) * Kdim + p0 * 8;
    const u16* gaA1 = A + (size_t)(m0 + 128 + r0) * Kdim + p0 * 8;
    const u16* gaB  = Bt + (size_t)(n0 + r0) * Kdim + p0 * 8;
    const int dA0 = (wid << 6) * 8;               // wave-uniform LDS bases
    const int dA1 = (512 + (wid << 6)) * 8;
    const int dB  = (wid << 6) * 8;

    auto stage = [&](int kt, int pb) {
        GLOAD_LDS16(gaA0 + kt, &sA[pb][dA0]);
        GLOAD_LDS16(gaA1 + kt, &sA[pb][dA1]);
        GLOAD_LDS16(gaB + kt, &sB[pb][dB]);
    };

    const int arow = (wm << 6) + (lane & 15);
    const int brow = (wn << 6) + (lane & 15);
    const int kg = (lane >> 4) * 8;

    const int niter = Kdim >> 5;
    stage(0, 0);
    for (int it = 0; it < niter; ++it) {
        const int cur = it & 1;
        __syncthreads();                  // stage(it) complete; prev reads of cur done
        if (it + 1 < niter) stage((it + 1) << 5, cur ^ 1);
        bf16x8 av[4], bw[4];
#pragma unroll
        for (int i = 0; i < 4; i++) av[i] = *(const bf16x8*)&sA[cur][(arow + i * 16) * 32 + kg];
#pragma unroll
        for (int j = 0; j < 4; j++) bw[j] = *(const bf16x8*)&sB[cur][(brow + j * 16) * 32 + kg];
#pragma unroll
        for (int i = 0; i < 4; i++)
#pragma unroll
            for (int j = 0; j < 4; j++) acc[i][j] = mfma16(av[i], bw[j], acc[i][j]);
    }

    const int col0 = n0 + (wn << 6) + (lane & 15);
    const int rowb = m0 + (wm << 6) + ((lane >> 4) << 2);
    float bvals[4];
#pragma unroll
    for (int j = 0; j < 4; j++) bvals[j] = bias[col0 + j * 16];

    if constexpr (SPLIT_VT) {
        if (n0 >= 1536) {     // V block: transposed write to VtG, skip normal C
            const int vcol0 = col0 - 1536;
#pragma unroll
            for (int i = 0; i < 4; i++) {
#pragma unroll
                for (int j = 0; j < 4; j++) {
                    u16x4 o4;
#pragma unroll
                    for (int rg = 0; rg < 4; rg++) o4[rg] = f2bf(acc[i][j][rg] + bvals[j]);
                    *(u16x4*)&VtGp[(size_t)(vcol0 + j * 16) * Rtot + rowb + i * 16] = o4;
                }
            }
            return;
        }
    }

#pragma unroll
    for (int i = 0; i < 4; i++) {
#pragma unroll
        for (int rg = 0; rg < 4; rg++) {
            const int row = rowb + i * 16 + rg;
            const float* rp = nullptr;
            if constexpr (ADD_RES)
                rp = (row < mvisL) ? resA + (size_t)row * 768
                                   : resB + (size_t)(row - mvisL) * 768;
#pragma unroll
            for (int j = 0; j < 4; j++) {
                const int col = col0 + j * 16;
                float v = acc[i][j][rg] + bvals[j];
                if constexpr (ADD_RES) v += rp[col];
                if constexpr (OUT_BF16)
                    ((u16*)Cout)[(size_t)row * Ndim + col] = f2bf(v);
                else
                    ((float*)Cout)[(size_t)row * Ndim + col] = v;
            }
        }
    }
}

// ---------- fused cross-attention (exact R15 kernel) ----------
// R7 sync structure (one barrier/step, K+V dbuf, stage(s+1) after barrier,
// serpentine). Swapped QK^T (S^T = mfma(K,Q)): lane holds P rows for q=lane&15,
// softmax = in-lane reduce + 2 shfl_xor; P quads feed 16x16x16 PV directly.
__global__ __launch_bounds__(512) void k_attn(const u16* __restrict__ qkv,
                                              const u16* __restrict__ VtG,
                                              const int* __restrict__ vmaskc,
                                              const int* __restrict__ tmaskc,
                                              u16* __restrict__ attn, int CHn, int Rtot) {
    __shared__ alignas(16) u16 Kl[2][128 * 128];   // 64 KB
    __shared__ alignas(16) u16 Vt[2][96 * 128];    // 48 KB
    __shared__ float mk[2][128];

    const int bx = blockIdx.x;
    int b, h, qbase, kbase, nqt, ntl;
    const int* mask;
    const int vcap = CHn * 8;
    if (bx < vcap) {   // visual queries attend to text: 4 passes x 256 rows
        b = bx >> 3; h = bx & 7;
        qbase = b << 10; kbase = (CHn << 10) + (b << 9);
        mask = tmaskc + (b << 9); nqt = 4; ntl = 2;   // ntile=4 (Sk=512)
    } else {           // text queries attend to visual: 2 passes x 256 rows
        const int bx2 = bx - vcap;
        b = bx2 >> 3; h = bx2 & 7;
        qbase = (CHn << 10) + (b << 9); kbase = b << 10;
        mask = vmaskc + (b << 10); nqt = 2; ntl = 3;  // ntile=8 (Sk=1024)
    }
    const int ntile = 1 << ntl;
    const int nsteps = nqt << ntl;
    const int tid = threadIdx.x, wid = tid >> 6, lane = tid & 63;
    const int l15 = lane & 15, l4 = lane >> 4;
    const float scale = 0.10206207261596577f;  // 1/sqrt(96)

    int koff[3];
#pragma unroll
    for (int kk = 0; kk < 3; kk++) koff[kk] = ((kk * 4 + l4) ^ (l15 & 7)) << 3;

    auto kt_of = [&](int s) {
        const int qt = s >> ntl, ktr = s & (ntile - 1);
        return (qt & 1) ? (ntile - 1 - ktr) : ktr;   // serpentine
    };
    auto stage = [&](int kt, int pb) {
#pragma unroll
        for (int it = 0; it < 4; ++it) {             // K tile: 2048 16B chunks
            const int cb = it * 512 + (wid << 6);
            const int c = cb + lane;
            const int r = c >> 4, s8 = c & 15;
            const int k8 = s8 ^ (r & 7);
            const u16* src = qkv + (size_t)(kbase + (kt << 7) + r) * 2304 + 768 + h * 96
                             + (k8 < 12 ? k8 * 8 : 0);
            GLOAD_LDS16(src, &Kl[pb][(size_t)cb * 8]);
        }
#pragma unroll
        for (int it = 0; it < 3; ++it) {             // V tile: 1536 16B chunks
            const int cb = it * 512 + (wid << 6);
            const int c = cb + lane;
            const int d = c >> 4, s8 = c & 15;
            const int k8 = s8 ^ (d & 7);
            const u16* src = VtG + (size_t)(h * 96 + d) * Rtot + kbase + (kt << 7) + k8 * 8;
            GLOAD_LDS16(src, &Vt[pb][(size_t)cb * 8]);
        }
        if (tid < 128) mk[pb][tid] = mask[(kt << 7) + tid] ? 0.f : -1e30f;
    };

    stage(kt_of(0), 0);
    int s = 0;
    for (int qt = 0; qt < nqt; ++qt) {
        bf16x8 aq[2][3];
#pragma unroll
        for (int qs = 0; qs < 2; ++qs) {
            const int qr = qbase + (qt << 8) + (wid << 5) + qs * 16 + l15;
#pragma unroll
            for (int kk = 0; kk < 3; kk++) {
                bf16x8 tq = *(const bf16x8*)&qkv[(size_t)qr * 2304 + h * 96 + kk * 32 + l4 * 8];
#pragma unroll
                for (int e = 0; e < 8; e++) tq[e] = (__bf16)((float)tq[e] * scale);
                aq[qs][kk] = tq;
            }
        }
        f32x4 o[2][6] = {};
        float mrunS[2] = {-1e30f, -1e30f};
        float lrunS[2] = {0.f, 0.f};

        for (int ktr = 0; ktr < ntile; ++ktr, ++s) {
            const int cur = s & 1;
            __syncthreads();                      // publish stage(cur); reads of cur^1 done
            if (s + 1 < nsteps) stage(kt_of(s + 1), cur ^ 1);

            // ---- S^T = K Q^T, j-outer (K fragments shared by both q-sets) ----
            f32x4 sc[2][8];
#pragma unroll
            for (int j = 0; j < 8; j++) {
                const int rbase = (j * 16 + l15) * 128;
                bf16x8 bk[3];
#pragma unroll
                for (int kk = 0; kk < 3; kk++)
                    bk[kk] = *(const bf16x8*)&Kl[cur][rbase + koff[kk]];
#pragma unroll
                for (int qs = 0; qs < 2; ++qs) {
                    f32x4 cj = {0.f, 0.f, 0.f, 0.f};
#pragma unroll
                    for (int kk = 0; kk < 3; kk++) cj = mfma16(bk[kk], aq[qs][kk], cj);
                    sc[qs][j] = cj;
                }
            }

            bf16x4v pb[2][8];
#pragma unroll
            for (int qs = 0; qs < 2; ++qs) {
                float tm = -1e30f;
#pragma unroll
                for (int j = 0; j < 8; j++) {
                    f32x4 m4 = *(const f32x4*)&mk[cur][j * 16 + (l4 << 2)];
#pragma unroll
                    for (int rg = 0; rg < 4; rg++) {
                        float v = sc[qs][j][rg] + m4[rg];
                        sc[qs][j][rg] = v;
                        tm = fmaxf(tm, v);
                    }
                }
                tm = fmaxf(tm, __shfl_xor(tm, 16));
                tm = fmaxf(tm, __shfl_xor(tm, 32));
                const int need = (tm > mrunS[qs] + 8.f) ? 1 : 0;
                if (__any(need)) {
                    float mn = fmaxf(mrunS[qs], tm);
                    float corrS = __expf(mrunS[qs] - mn);
                    mrunS[qs] = mn;
                    lrunS[qs] *= corrS;
                    float cr[4];
#pragma unroll
                    for (int rg = 0; rg < 4; rg++) cr[rg] = __shfl(corrS, (l4 << 2) + rg);
#pragma unroll
                    for (int j6 = 0; j6 < 6; j6++)
#pragma unroll
                        for (int rg = 0; rg < 4; rg++) o[qs][j6][rg] *= cr[rg];
                }
                float ts = 0.f;
#pragma unroll
                for (int j = 0; j < 8; j++) {
                    bf16x4v pq;
#pragma unroll
                    for (int rg = 0; rg < 4; rg++) {
                        float p = __expf(sc[qs][j][rg] - mrunS[qs]);
                        ts += p;
                        pq[rg] = (__bf16)p;
                    }
                    pb[qs][j] = pq;
                }
                ts += __shfl_xor(ts, 16);
                ts += __shfl_xor(ts, 32);
                lrunS[qs] += ts;
            }

            // ---- O += P V via 16x16x16 MFMA; V b64 reads shared by both q-sets ----
#pragma unroll
            for (int j = 0; j < 8; j++) {
                const int slotb = 2 * j + (l4 >> 1);
                const int intra = (l4 & 1) << 2;
#pragma unroll
                for (int j6 = 0; j6 < 6; j6++) {
                    const int d = j6 * 16 + l15;
                    bf16x4v bv = *(const bf16x4v*)&Vt[cur][d * 128 +
                                     ((slotb ^ (l15 & 7)) << 3) + intra];
                    o[0][j6] = mfma16k16(pb[0][j], bv, o[0][j6]);
                    o[1][j6] = mfma16k16(pb[1][j], bv, o[1][j6]);
                }
            }
        }

#pragma unroll
        for (int qs = 0; qs < 2; ++qs) {
            const float invS = 1.f / lrunS[qs];
            float inv[4];
#pragma unroll
            for (int rg = 0; rg < 4; rg++) inv[rg] = __shfl(invS, (l4 << 2) + rg);
            const size_t orow = (size_t)(qbase + (qt << 8) + (wid << 5) + qs * 16);
#pragma unroll
            for (int j6 = 0; j6 < 6; j6++)
#pragma unroll
                for (int rg = 0; rg < 4; rg++)
                    attn[(orow + l4 * 4 + rg) * 768 + h * 96 + j6 * 16 + l15] =
                        f2bf(o[qs][j6][rg] * inv[rg]);
        }
    }
}

// ---------- LN1 + masked-pool accumulation (bf16 input) ----------
__global__ __launch_bounds__(256) void k_ln_pool(const u16* __restrict__ X,
                                                 const int* __restrict__ vmaskc,
                                                 const int* __restrict__ tmaskc,
                                                 const float* __restrict__ g,
                                                 const float* __restrict__ bb,
                                                 float* __restrict__ pooled,
                                                 int mvisL, int bg0) {
    __shared__ float pool[768];
    const int tid = threadIdx.x, wid = tid >> 6, lane = tid & 63;
    const int row0 = blockIdx.x << 5;
    const bool vis = row0 < mvisL;
    const int* mask = vis ? vmaskc : tmaskc;
    const int mbase = vis ? 0 : mvisL;
    const int bl = vis ? (row0 >> 10) : ((row0 - mvisL) >> 9);
    float* pout = pooled + (vis ? 0 : 12288) + (size_t)(bg0 + bl) * 768;

    float gv[12], bv2[12];
#pragma unroll
    for (int k = 0; k < 12; k++) { gv[k] = g[lane + k * 64]; bv2[k] = bb[lane + k * 64]; }
    float acc[12] = {};
    for (int rr = 0; rr < 8; ++rr) {
        const int row = row0 + (wid << 3) + rr;
        const u16* x = X + (size_t)row * 768;
        float xs[12], sm = 0.f, s2 = 0.f;
#pragma unroll
        for (int k = 0; k < 12; k++) {
            float tv = bf2f(x[lane + k * 64]);
            xs[k] = tv; sm += tv; s2 += tv * tv;
        }
#pragma unroll
        for (int d = 1; d < 64; d <<= 1) { sm += __shfl_xor(sm, d); s2 += __shfl_xor(s2, d); }
        const float mean = sm * (1.f / 768.f);
        const float rstd = rsqrtf(s2 * (1.f / 768.f) - mean * mean + 1e-5f);
        const float mv = (float)mask[row - mbase];
#pragma unroll
        for (int k = 0; k < 12; k++) acc[k] += ((xs[k] - mean) * rstd * gv[k] + bv2[k]) * mv;
    }
    pool[tid] = 0.f; pool[tid + 256] = 0.f; pool[tid + 512] = 0.f;
    __syncthreads();
#pragma unroll
    for (int k = 0; k < 12; k++) atomicAdd(&pool[lane + k * 64], acc[k]);
    __syncthreads();
    atomicAdd(&pout[tid], pool[tid]);
    atomicAdd(&pout[tid + 256], pool[tid + 256]);
    atomicAdd(&pout[tid + 512], pool[tid + 512]);
}

// ---------- final ----------
__device__ __forceinline__ float blk_sum(float v, volatile float* tmp) {
#pragma unroll
    for (int d = 1; d < 64; d <<= 1) v += __shfl_xor(v, d);
    __syncthreads();
    if ((threadIdx.x & 63) == 0) tmp[threadIdx.x >> 6] = v;
    __syncthreads();
    return tmp[0] + tmp[1] + tmp[2] + tmp[3];
}

// mask counts, pooled concat @ Wf + bf (wave-split over K=1536), LN2
__global__ __launch_bounds__(256) void k_final(const float* __restrict__ pooled,
                                               const int* __restrict__ vmask,
                                               const int* __restrict__ tmask,
                                               const float* __restrict__ Wf,
                                               const float* __restrict__ bfv,
                                               const float* __restrict__ g2,
                                               const float* __restrict__ b2,
                                               float* __restrict__ out) {
    __shared__ float sh[1536];
    __shared__ float red[4];
    __shared__ float pf[4][12][64];
    const int b = blockIdx.x, tid = threadIdx.x;
    const int wid = tid >> 6, lane = tid & 63;
    float cv = 0.f, ct = 0.f;
    for (int i = tid; i < 1024; i += 256) cv += (float)vmask[(b << 10) + i];
    for (int i = tid; i < 512; i += 256) ct += (float)tmask[(b << 9) + i];
    cv = blk_sum(cv, red);
    ct = blk_sum(ct, red);
    const float iv = 1.f / cv, itv = 1.f / ct;
#pragma unroll
    for (int k = 0; k < 3; k++) {
        int j = tid + (k << 8);
        sh[j] = pooled[b * 768 + j] * iv;
        sh[768 + j] = pooled[12288 + b * 768 + j] * itv;
    }
    __syncthreads();
    // wave wid scans K-range [wid*384, wid*384+384) for 12 column partials
    float fp[12] = {};
    for (int i = wid * 384; i < wid * 384 + 384; i++) {
        const float pv = sh[i];
        const float* w = Wf + (size_t)i * 768 + lane;
#pragma unroll
        for (int c = 0; c < 12; c++) fp[c] += pv * w[c * 64];
    }
#pragma unroll
    for (int c = 0; c < 12; c++) pf[wid][c][lane] = fp[c];
    __syncthreads();
    float f0 = bfv[tid], f1 = bfv[tid + 256], f2 = bfv[tid + 512];
#pragma unroll
    for (int w4 = 0; w4 < 4; w4++) {
        f0 += pf[w4][wid][lane];
        f1 += pf[w4][wid + 4][lane];
        f2 += pf[w4][wid + 8][lane];
    }
    float sm = blk_sum(f0 + f1 + f2, red);
    float s2 = blk_sum(f0 * f0 + f1 * f1 + f2 * f2, red);
    const float mean = sm * (1.f / 768.f);
    const float rstd = rsqrtf(s2 * (1.f / 768.f) - mean * mean + 1e-5f);
    out[b * 768 + tid] = (f0 - mean) * rstd * g2[tid] + b2[tid];
    out[b * 768 + tid + 256] = (f1 - mean) * rstd * g2[tid + 256] + b2[tid + 256];
    out[b * 768 + tid + 512] = (f2 - mean) * rstd * g2[tid + 512] + b2[tid + 512];
}

// ---------- host ----------
extern "C" void kernel_launch(void* const* d_in, const int* in_sizes, int n_in,
                              void* d_out, int out_size, void* d_ws, size_t ws_size,
                              hipStream_t stream) {
    (void)in_sizes; (void)n_in; (void)out_size;
    const float* vf = (const float*)d_in[0];
    const float* tf = (const float*)d_in[1];
    const int* vmask = (const int*)d_in[2];
    const int* tmask = (const int*)d_in[3];
    const float* Wq = (const float*)d_in[4];
    const float* bq = (const float*)d_in[5];
    const float* Wk = (const float*)d_in[6];
    const float* bk = (const float*)d_in[7];
    const float* Wv = (const float*)d_in[8];
    const float* bv = (const float*)d_in[9];
    const float* Wo = (const float*)d_in[10];
    const float* bo = (const float*)d_in[11];
    const float* g1 = (const float*)d_in[12];
    const float* b1 = (const float*)d_in[13];
    const float* Wf = (const float*)d_in[14];
    const float* bfv = (const float*)d_in[15];
    const float* g2 = (const float*)d_in[16];
    const float* b2 = (const float*)d_in[17];
    float* outp = (float*)d_out;

    // footprint = 4,826,112 + CH * (2,359,296 X + 7,077,888 QKV + 2,359,296 VtG)
    int CH = 16;
    while (CH > 1 && 4826112ull + (size_t)CH * 11796480ull > ws_size) CH >>= 1;
    const int NC = 16 / CH;
    const int Rtot = CH * 1536;

    char* ws = (char*)d_ws;
    u16*   wsW      = (u16*)(ws);
    u16*   wsWo     = (u16*)(ws + 3538944);
    float* wsBqkv   = (float*)(ws + 4718592);
    float* wsPooled = (float*)(ws + 4727808);
    u16*   wsX      = (u16*)(ws + 4826112);                 // [R][768] bf16 (reused: attn out)
    char*  qkvBase  = ws + 4826112 + (size_t)CH * 2359296;
    u16*   wsQKV    = (u16*)qkvBase;                         // [R][2304] bf16 (reused: Oproj bf16)
    u16*   wsOproj  = (u16*)qkvBase;
    u16*   wsVtG    = (u16*)(qkvBase + (size_t)CH * 7077888);// [768][R] bf16
    u16*   wsAttn   = wsX;

    k_transpose<<<dim3(144), dim3(256), 0, stream>>>(Wq, wsW, 768, 768);
    k_transpose<<<dim3(144), dim3(256), 0, stream>>>(Wk, wsW + 589824, 768, 768);
    k_transpose<<<dim3(144), dim3(256), 0, stream>>>(Wv, wsW + 1179648, 768, 768);
    k_transpose<<<dim3(144), dim3(256), 0, stream>>>(Wo, wsWo, 768, 768);
    k_bias<<<dim3(9), dim3(256), 0, stream>>>(bq, bk, bv, wsBqkv);
    k_zero<<<dim3(96), dim3(256), 0, stream>>>(wsPooled);

    for (int c = 0; c < NC; ++c) {
        const float* vfc = vf + (size_t)c * CH * 1024 * 768;
        const float* tfc = tf + (size_t)c * CH * 512 * 768;
        const int* vmc = vmask + c * CH * 1024;
        const int* tmc = tmask + c * CH * 512;

        k_cvt_x<<<dim3(CH * 1152), dim3(256), 0, stream>>>(vfc, tfc, wsX, CH * 196608);

        // QKV GEMM (256x128 tiles); V third written transposed directly into VtG
        k_gemm<true, false, true><<<dim3(CH * 108), dim3(512), 0, stream>>>(
            wsX, wsW, wsBqkv, nullptr, nullptr, (void*)wsQKV, 2304, 768, 0, wsVtG, Rtot);

        k_attn<<<dim3(CH * 16), dim3(512), 0, stream>>>(
            wsQKV, wsVtG, vmc, tmc, wsAttn, CH, Rtot);

        // O-proj + bias + residual, bf16 out
        k_gemm<true, true, false><<<dim3(CH * 36), dim3(512), 0, stream>>>(
            wsAttn, wsWo, bo, vfc, tfc, (void*)wsOproj, 768, 768, CH * 1024, nullptr, 0);

        k_ln_pool<<<dim3(CH * 48), dim3(256), 0, stream>>>(
            wsOproj, vmc, tmc, g1, b1, wsPooled, CH * 1024, c * CH);
    }

    k_final<<<dim3(16), dim3(256), 0, stream>>>(wsPooled, vmask, tmask, Wf, bfv, g2, b2, outp);
}

// Round 17
// 379.964 us; speedup vs baseline: 1.2087x; 1.0005x over previous
//
#include <hip/hip_runtime.h>

typedef __bf16 bf16x8 __attribute__((ext_vector_type(8)));
typedef __bf16 bf16x4v __attribute__((ext_vector_type(4)));
typedef short s16x4 __attribute__((ext_vector_type(4)));
typedef float f32x4 __attribute__((ext_vector_type(4)));
typedef unsigned short u16;
typedef unsigned int u32;
typedef u16 u16x8 __attribute__((ext_vector_type(8)));
typedef u16 u16x4 __attribute__((ext_vector_type(4)));

// B=16, SV=1024, ST=512, D=768, H=8, DH=96. Chunked over CH batches,
// R = CH*1536 rows (CH*1024 visual then CH*512 text).

__device__ __forceinline__ u16 f2bf(float f) {
    u32 u = __builtin_bit_cast(u32, f);
    u32 r = u + 0x7FFFu + ((u >> 16) & 1u);
    return (u16)(r >> 16);
}

__device__ __forceinline__ float bf2f(u16 b) {
    u32 u = ((u32)b) << 16;
    return __builtin_bit_cast(float, u);
}

__device__ __forceinline__ f32x4 mfma16(bf16x8 a, bf16x8 b, f32x4 c) {
    return __builtin_amdgcn_mfma_f32_16x16x32_bf16(a, b, c, 0, 0, 0);
}

// 16x16x16 bf16 MFMA (A/B = 4 bf16/lane, k = (lane>>4)*4+e)
__device__ __forceinline__ f32x4 mfma16k16(bf16x4v a, bf16x4v b, f32x4 c) {
#if __has_builtin(__builtin_amdgcn_mfma_f32_16x16x16_bf16)
    return __builtin_amdgcn_mfma_f32_16x16x16_bf16(a, b, c, 0, 0, 0);
#elif __has_builtin(__builtin_amdgcn_mfma_f32_16x16x16bf16_1k)
    return __builtin_amdgcn_mfma_f32_16x16x16bf16_1k(
        __builtin_bit_cast(s16x4, a), __builtin_bit_cast(s16x4, b), c, 0, 0, 0);
#else
    f32x4 d;
    asm volatile("v_mfma_f32_16x16x16_bf16 %0, %1, %2, %3"
                 : "=v"(d) : "v"(a), "v"(b), "v"(c));
    return d;
#endif
}

#define GLOAD_LDS16(g, l) __builtin_amdgcn_global_load_lds( \
    (__attribute__((address_space(1))) void*)(g), \
    (__attribute__((address_space(3))) void*)(l), 16, 0, 0)

// ---------- prep kernels ----------

__global__ __launch_bounds__(256) void k_cvt_x(const float* __restrict__ vf,
                                               const float* __restrict__ tf,
                                               u16* __restrict__ X, int nvis4) {
    int i = blockIdx.x * 256 + threadIdx.x;
    f32x4 v = (i < nvis4) ? ((const f32x4*)vf)[i] : ((const f32x4*)tf)[i - nvis4];
    u16x4 o = { f2bf(v[0]), f2bf(v[1]), f2bf(v[2]), f2bf(v[3]) };
    ((u16x4*)X)[i] = o;
}

// src f32 [K0][N0] -> dst bf16 [N0][K0]   (64x64 LDS tiles)
__global__ __launch_bounds__(256) void k_transpose(const float* __restrict__ src,
                                                   u16* __restrict__ dst,
                                                   int K0, int N0) {
    __shared__ float t[64][65];
    int ntx = N0 >> 6;
    int k0 = (blockIdx.x / ntx) << 6, n0 = (blockIdx.x % ntx) << 6;
    int c = threadIdx.x & 63, rr = threadIdx.x >> 6;
#pragma unroll
    for (int q = 0; q < 16; q++) {
        int r = q * 4 + rr;
        t[r][c] = src[(size_t)(k0 + r) * N0 + n0 + c];
    }
    __syncthreads();
#pragma unroll
    for (int q = 0; q < 16; q++) {
        int r = q * 4 + rr;
        dst[(size_t)(n0 + r) * K0 + k0 + c] = f2bf(t[c][r]);
    }
}

__global__ __launch_bounds__(256) void k_bias(const float* __restrict__ bq,
                                              const float* __restrict__ bk,
                                              const float* __restrict__ bv,
                                              float* __restrict__ bqkv) {
    int n = blockIdx.x * 256 + threadIdx.x;
    if (n < 2304) {
        const float* s = (n < 768) ? bq : ((n < 1536) ? bk : bv);
        int r = (n < 768) ? n : ((n < 1536) ? n - 768 : n - 1536);
        bqkv[n] = s[r];
    }
}

__global__ __launch_bounds__(256) void k_zero(float* __restrict__ p) {
    p[blockIdx.x * 256 + threadIdx.x] = 0.f;
}

// ---------- GEMM: C[R][N] = A[R][K] * Bt[N][K]^T + bias (+residual) ----------
// 256x128 tile, BK=32, 8 waves (4m x 2n), 512 threads. Same 2-phase sync as
// R12-R15 (dbuf LDS, ONE __syncthreads per K-step, stage(it+1) after barrier).
// LDS 48KB -> 3 blocks/CU (24 waves) for latency hiding.
// XCD-chunked blockIdx swizzle only when grid % 8 == 0 (bijectivity).
template <bool OUT_BF16, bool ADD_RES, bool SPLIT_VT>
__global__ __launch_bounds__(512) void k_gemm(const u16* __restrict__ A,
                                              const u16* __restrict__ Bt,
                                              const float* __restrict__ bias,
                                              const float* __restrict__ resA,
                                              const float* __restrict__ resB,
                                              void* __restrict__ Cout,
                                              int Ndim, int Kdim, int mvisL,
                                              u16* __restrict__ VtGp, int Rtot) {
    __shared__ alignas(16) u16 sA[2][256 * 32];   // 32 KB
    __shared__ alignas(16) u16 sB[2][128 * 32];   // 16 KB
    const int tid = threadIdx.x, wid = tid >> 6, lane = tid & 63;
    const int nwg = gridDim.x;
    const int wg = (nwg & 7) ? (int)blockIdx.x
                             : ((blockIdx.x & 7) * (nwg >> 3) + (blockIdx.x >> 3));
    const int ntiles = Ndim >> 7;
    const int mt = wg / ntiles, nt = wg - mt * ntiles;
    const int m0 = mt << 8, n0 = nt << 7;
    const int wm = wid >> 1, wn = wid & 1;        // 4m x 2n waves, 64x64 each
    f32x4 acc[4][4] = {};

    // staging: A granules g=tid (rows 0..127) and g=512+tid (rows 128..255);
    // B granules g=tid (rows 0..127). granule -> r=g>>2, chunk p=g&3.
    const int r0 = tid >> 2, p0 = tid & 3;
    const u16* gaA0 = A + (size_t)(m0 + r0) * Kdim + p0 * 8;
    const u16* gaA1 = A + (size_t)(m0 + 128 + r0) * Kdim + p0 * 8;
    const u16* gaB  = Bt + (size_t)(n0 + r0) * Kdim + p0 * 8;
    const int dA0 = (wid << 6) * 8;               // wave-uniform LDS bases
    const int dA1 = (512 + (wid << 6)) * 8;
    const int dB  = (wid << 6) * 8;

    auto stage = [&](int kt, int pb) {
        GLOAD_LDS16(gaA0 + kt, &sA[pb][dA0]);
        GLOAD_LDS16(gaA1 + kt, &sA[pb][dA1]);
        GLOAD_LDS16(gaB + kt, &sB[pb][dB]);
    };

    const int arow = (wm << 6) + (lane & 15);
    const int brow = (wn << 6) + (lane & 15);
    const int kg = (lane >> 4) * 8;

    const int niter = Kdim >> 5;
    stage(0, 0);
    for (int it = 0; it < niter; ++it) {
        const int cur = it & 1;
        __syncthreads();                  // stage(it) complete; prev reads of cur done
        if (it + 1 < niter) stage((it + 1) << 5, cur ^ 1);
        bf16x8 av[4], bw[4];
#pragma unroll
        for (int i = 0; i < 4; i++) av[i] = *(const bf16x8*)&sA[cur][(arow + i * 16) * 32 + kg];
#pragma unroll
        for (int j = 0; j < 4; j++) bw[j] = *(const bf16x8*)&sB[cur][(brow + j * 16) * 32 + kg];
#pragma unroll
        for (int i = 0; i < 4; i++)
#pragma unroll
            for (int j = 0; j < 4; j++) acc[i][j] = mfma16(av[i], bw[j], acc[i][j]);
    }

    const int col0 = n0 + (wn << 6) + (lane & 15);
    const int rowb = m0 + (wm << 6) + ((lane >> 4) << 2);
    float bvals[4];
#pragma unroll
    for (int j = 0; j < 4; j++) bvals[j] = bias[col0 + j * 16];

    if constexpr (SPLIT_VT) {
        if (n0 >= 1536) {     // V block: transposed write to VtG, skip normal C
            const int vcol0 = col0 - 1536;
#pragma unroll
            for (int i = 0; i < 4; i++) {
#pragma unroll
                for (int j = 0; j < 4; j++) {
                    u16x4 o4;
#pragma unroll
                    for (int rg = 0; rg < 4; rg++) o4[rg] = f2bf(acc[i][j][rg] + bvals[j]);
                    *(u16x4*)&VtGp[(size_t)(vcol0 + j * 16) * Rtot + rowb + i * 16] = o4;
                }
            }
            return;
        }
    }

#pragma unroll
    for (int i = 0; i < 4; i++) {
#pragma unroll
        for (int rg = 0; rg < 4; rg++) {
            const int row = rowb + i * 16 + rg;
            const float* rp = nullptr;
            if constexpr (ADD_RES)
                rp = (row < mvisL) ? resA + (size_t)row * 768
                                   : resB + (size_t)(row - mvisL) * 768;
#pragma unroll
            for (int j = 0; j < 4; j++) {
                const int col = col0 + j * 16;
                float v = acc[i][j][rg] + bvals[j];
                if constexpr (ADD_RES) v += rp[col];
                if constexpr (OUT_BF16)
                    ((u16*)Cout)[(size_t)row * Ndim + col] = f2bf(v);
                else
                    ((float*)Cout)[(size_t)row * Ndim + col] = v;
            }
        }
    }
}

// ---------- fused cross-attention (exact R15 kernel) ----------
// R7 sync structure (one barrier/step, K+V dbuf, stage(s+1) after barrier,
// serpentine). Swapped QK^T (S^T = mfma(K,Q)): lane holds P rows for q=lane&15,
// softmax = in-lane reduce + 2 shfl_xor; P quads feed 16x16x16 PV directly.
__global__ __launch_bounds__(512) void k_attn(const u16* __restrict__ qkv,
                                              const u16* __restrict__ VtG,
                                              const int* __restrict__ vmaskc,
                                              const int* __restrict__ tmaskc,
                                              u16* __restrict__ attn, int CHn, int Rtot) {
    __shared__ alignas(16) u16 Kl[2][128 * 128];   // 64 KB
    __shared__ alignas(16) u16 Vt[2][96 * 128];    // 48 KB
    __shared__ float mk[2][128];

    const int bx = blockIdx.x;
    int b, h, qbase, kbase, nqt, ntl;
    const int* mask;
    const int vcap = CHn * 8;
    if (bx < vcap) {   // visual queries attend to text: 4 passes x 256 rows
        b = bx >> 3; h = bx & 7;
        qbase = b << 10; kbase = (CHn << 10) + (b << 9);
        mask = tmaskc + (b << 9); nqt = 4; ntl = 2;   // ntile=4 (Sk=512)
    } else {           // text queries attend to visual: 2 passes x 256 rows
        const int bx2 = bx - vcap;
        b = bx2 >> 3; h = bx2 & 7;
        qbase = (CHn << 10) + (b << 9); kbase = b << 10;
        mask = vmaskc + (b << 10); nqt = 2; ntl = 3;  // ntile=8 (Sk=1024)
    }
    const int ntile = 1 << ntl;
    const int nsteps = nqt << ntl;
    const int tid = threadIdx.x, wid = tid >> 6, lane = tid & 63;
    const int l15 = lane & 15, l4 = lane >> 4;
    const float scale = 0.10206207261596577f;  // 1/sqrt(96)

    int koff[3];
#pragma unroll
    for (int kk = 0; kk < 3; kk++) koff[kk] = ((kk * 4 + l4) ^ (l15 & 7)) << 3;

    auto kt_of = [&](int s) {
        const int qt = s >> ntl, ktr = s & (ntile - 1);
        return (qt & 1) ? (ntile - 1 - ktr) : ktr;   // serpentine
    };
    auto stage = [&](int kt, int pb) {
#pragma unroll
        for (int it = 0; it < 4; ++it) {             // K tile: 2048 16B chunks
            const int cb = it * 512 + (wid << 6);
            const int c = cb + lane;
            const int r = c >> 4, s8 = c & 15;
            const int k8 = s8 ^ (r & 7);
            const u16* src = qkv + (size_t)(kbase + (kt << 7) + r) * 2304 + 768 + h * 96
                             + (k8 < 12 ? k8 * 8 : 0);
            GLOAD_LDS16(src, &Kl[pb][(size_t)cb * 8]);
        }
#pragma unroll
        for (int it = 0; it < 3; ++it) {             // V tile: 1536 16B chunks
            const int cb = it * 512 + (wid << 6);
            const int c = cb + lane;
            const int d = c >> 4, s8 = c & 15;
            const int k8 = s8 ^ (d & 7);
            const u16* src = VtG + (size_t)(h * 96 + d) * Rtot + kbase + (kt << 7) + k8 * 8;
            GLOAD_LDS16(src, &Vt[pb][(size_t)cb * 8]);
        }
        if (tid < 128) mk[pb][tid] = mask[(kt << 7) + tid] ? 0.f : -1e30f;
    };

    stage(kt_of(0), 0);
    int s = 0;
    for (int qt = 0; qt < nqt; ++qt) {
        bf16x8 aq[2][3];
#pragma unroll
        for (int qs = 0; qs < 2; ++qs) {
            const int qr = qbase + (qt << 8) + (wid << 5) + qs * 16 + l15;
#pragma unroll
            for (int kk = 0; kk < 3; kk++) {
                bf16x8 tq = *(const bf16x8*)&qkv[(size_t)qr * 2304 + h * 96 + kk * 32 + l4 * 8];
#pragma unroll
                for (int e = 0; e < 8; e++) tq[e] = (__bf16)((float)tq[e] * scale);
                aq[qs][kk] = tq;
            }
        }
        f32x4 o[2][6] = {};
        float mrunS[2] = {-1e30f, -1e30f};
        float lrunS[2] = {0.f, 0.f};

        for (int ktr = 0; ktr < ntile; ++ktr, ++s) {
            const int cur = s & 1;
            __syncthreads();                      // publish stage(cur); reads of cur^1 done
            if (s + 1 < nsteps) stage(kt_of(s + 1), cur ^ 1);

            // ---- S^T = K Q^T, j-outer (K fragments shared by both q-sets) ----
            f32x4 sc[2][8];
#pragma unroll
            for (int j = 0; j < 8; j++) {
                const int rbase = (j * 16 + l15) * 128;
                bf16x8 bk[3];
#pragma unroll
                for (int kk = 0; kk < 3; kk++)
                    bk[kk] = *(const bf16x8*)&Kl[cur][rbase + koff[kk]];
#pragma unroll
                for (int qs = 0; qs < 2; ++qs) {
                    f32x4 cj = {0.f, 0.f, 0.f, 0.f};
#pragma unroll
                    for (int kk = 0; kk < 3; kk++) cj = mfma16(bk[kk], aq[qs][kk], cj);
                    sc[qs][j] = cj;
                }
            }

            bf16x4v pb[2][8];
#pragma unroll
            for (int qs = 0; qs < 2; ++qs) {
                float tm = -1e30f;
#pragma unroll
                for (int j = 0; j < 8; j++) {
                    f32x4 m4 = *(const f32x4*)&mk[cur][j * 16 + (l4 << 2)];
#pragma unroll
                    for (int rg = 0; rg < 4; rg++) {
                        float v = sc[qs][j][rg] + m4[rg];
                        sc[qs][j][rg] = v;
                        tm = fmaxf(tm, v);
                    }
                }
                tm = fmaxf(tm, __shfl_xor(tm, 16));
                tm = fmaxf(tm, __shfl_xor(tm, 32));
                const int need = (tm > mrunS[qs] + 8.f) ? 1 : 0;
                if (__any(need)) {
                    float mn = fmaxf(mrunS[qs], tm);
                    float corrS = __expf(mrunS[qs] - mn);
                    mrunS[qs] = mn;
                    lrunS[qs] *= corrS;
                    float cr[4];
#pragma unroll
                    for (int rg = 0; rg < 4; rg++) cr[rg] = __shfl(corrS, (l4 << 2) + rg);
#pragma unroll
                    for (int j6 = 0; j6 < 6; j6++)
#pragma unroll
                        for (int rg = 0; rg < 4; rg++) o[qs][j6][rg] *= cr[rg];
                }
                float ts = 0.f;
#pragma unroll
                for (int j = 0; j < 8; j++) {
                    bf16x4v pq;
#pragma unroll
                    for (int rg = 0; rg < 4; rg++) {
                        float p = __expf(sc[qs][j][rg] - mrunS[qs]);
                        ts += p;
                        pq[rg] = (__bf16)p;
                    }
                    pb[qs][j] = pq;
                }
                ts += __shfl_xor(ts, 16);
                ts += __shfl_xor(ts, 32);
                lrunS[qs] += ts;
            }

            // ---- O += P V via 16x16x16 MFMA; V b64 reads shared by both q-sets ----
#pragma unroll
            for (int j = 0; j < 8; j++) {
                const int slotb = 2 * j + (l4 >> 1);
                const int intra = (l4 & 1) << 2;
#pragma unroll
                for (int j6 = 0; j6 < 6; j6++) {
                    const int d = j6 * 16 + l15;
                    bf16x4v bv = *(const bf16x4v*)&Vt[cur][d * 128 +
                                     ((slotb ^ (l15 & 7)) << 3) + intra];
                    o[0][j6] = mfma16k16(pb[0][j], bv, o[0][j6]);
                    o[1][j6] = mfma16k16(pb[1][j], bv, o[1][j6]);
                }
            }
        }

#pragma unroll
        for (int qs = 0; qs < 2; ++qs) {
            const float invS = 1.f / lrunS[qs];
            float inv[4];
#pragma unroll
            for (int rg = 0; rg < 4; rg++) inv[rg] = __shfl(invS, (l4 << 2) + rg);
            const size_t orow = (size_t)(qbase + (qt << 8) + (wid << 5) + qs * 16);
#pragma unroll
            for (int j6 = 0; j6 < 6; j6++)
#pragma unroll
                for (int rg = 0; rg < 4; rg++)
                    attn[(orow + l4 * 4 + rg) * 768 + h * 96 + j6 * 16 + l15] =
                        f2bf(o[qs][j6][rg] * inv[rg]);
        }
    }
}

// ---------- LN1 + masked-pool accumulation (bf16 input) ----------
__global__ __launch_bounds__(256) void k_ln_pool(const u16* __restrict__ X,
                                                 const int* __restrict__ vmaskc,
                                                 const int* __restrict__ tmaskc,
                                                 const float* __restrict__ g,
                                                 const float* __restrict__ bb,
                                                 float* __restrict__ pooled,
                                                 int mvisL, int bg0) {
    __shared__ float pool[768];
    const int tid = threadIdx.x, wid = tid >> 6, lane = tid & 63;
    const int row0 = blockIdx.x << 5;
    const bool vis = row0 < mvisL;
    const int* mask = vis ? vmaskc : tmaskc;
    const int mbase = vis ? 0 : mvisL;
    const int bl = vis ? (row0 >> 10) : ((row0 - mvisL) >> 9);
    float* pout = pooled + (vis ? 0 : 12288) + (size_t)(bg0 + bl) * 768;

    float gv[12], bv2[12];
#pragma unroll
    for (int k = 0; k < 12; k++) { gv[k] = g[lane + k * 64]; bv2[k] = bb[lane + k * 64]; }
    float acc[12] = {};
    for (int rr = 0; rr < 8; ++rr) {
        const int row = row0 + (wid << 3) + rr;
        const u16* x = X + (size_t)row * 768;
        float xs[12], sm = 0.f, s2 = 0.f;
#pragma unroll
        for (int k = 0; k < 12; k++) {
            float tv = bf2f(x[lane + k * 64]);
            xs[k] = tv; sm += tv; s2 += tv * tv;
        }
#pragma unroll
        for (int d = 1; d < 64; d <<= 1) { sm += __shfl_xor(sm, d); s2 += __shfl_xor(s2, d); }
        const float mean = sm * (1.f / 768.f);
        const float rstd = rsqrtf(s2 * (1.f / 768.f) - mean * mean + 1e-5f);
        const float mv = (float)mask[row - mbase];
#pragma unroll
        for (int k = 0; k < 12; k++) acc[k] += ((xs[k] - mean) * rstd * gv[k] + bv2[k]) * mv;
    }
    pool[tid] = 0.f; pool[tid + 256] = 0.f; pool[tid + 512] = 0.f;
    __syncthreads();
#pragma unroll
    for (int k = 0; k < 12; k++) atomicAdd(&pool[lane + k * 64], acc[k]);
    __syncthreads();
    atomicAdd(&pout[tid], pool[tid]);
    atomicAdd(&pout[tid + 256], pool[tid + 256]);
    atomicAdd(&pout[tid + 512], pool[tid + 512]);
}

// ---------- final ----------
__device__ __forceinline__ float blk_sum(float v, volatile float* tmp) {
#pragma unroll
    for (int d = 1; d < 64; d <<= 1) v += __shfl_xor(v, d);
    __syncthreads();
    if ((threadIdx.x & 63) == 0) tmp[threadIdx.x >> 6] = v;
    __syncthreads();
    return tmp[0] + tmp[1] + tmp[2] + tmp[3];
}

// mask counts, pooled concat @ Wf + bf (wave-split over K=1536), LN2
__global__ __launch_bounds__(256) void k_final(const float* __restrict__ pooled,
                                               const int* __restrict__ vmask,
                                               const int* __restrict__ tmask,
                                               const float* __restrict__ Wf,
                                               const float* __restrict__ bfv,
                                               const float* __restrict__ g2,
                                               const float* __restrict__ b2,
                                               float* __restrict__ out) {
    __shared__ float sh[1536];
    __shared__ float red[4];
    __shared__ float pf[4][12][64];
    const int b = blockIdx.x, tid = threadIdx.x;
    const int wid = tid >> 6, lane = tid & 63;
    float cv = 0.f, ct = 0.f;
    for (int i = tid; i < 1024; i += 256) cv += (float)vmask[(b << 10) + i];
    for (int i = tid; i < 512; i += 256) ct += (float)tmask[(b << 9) + i];
    cv = blk_sum(cv, red);
    ct = blk_sum(ct, red);
    const float iv = 1.f / cv, itv = 1.f / ct;
#pragma unroll
    for (int k = 0; k < 3; k++) {
        int j = tid + (k << 8);
        sh[j] = pooled[b * 768 + j] * iv;
        sh[768 + j] = pooled[12288 + b * 768 + j] * itv;
    }
    __syncthreads();
    // wave wid scans K-range [wid*384, wid*384+384) for 12 column partials
    float fp[12] = {};
    for (int i = wid * 384; i < wid * 384 + 384; i++) {
        const float pv = sh[i];
        const float* w = Wf + (size_t)i * 768 + lane;
#pragma unroll
        for (int c = 0; c < 12; c++) fp[c] += pv * w[c * 64];
    }
#pragma unroll
    for (int c = 0; c < 12; c++) pf[wid][c][lane] = fp[c];
    __syncthreads();
    float f0 = bfv[tid], f1 = bfv[tid + 256], f2 = bfv[tid + 512];
#pragma unroll
    for (int w4 = 0; w4 < 4; w4++) {
        f0 += pf[w4][wid][lane];
        f1 += pf[w4][wid + 4][lane];
        f2 += pf[w4][wid + 8][lane];
    }
    float sm = blk_sum(f0 + f1 + f2, red);
    float s2 = blk_sum(f0 * f0 + f1 * f1 + f2 * f2, red);
    const float mean = sm * (1.f / 768.f);
    const float rstd = rsqrtf(s2 * (1.f / 768.f) - mean * mean + 1e-5f);
    out[b * 768 + tid] = (f0 - mean) * rstd * g2[tid] + b2[tid];
    out[b * 768 + tid + 256] = (f1 - mean) * rstd * g2[tid + 256] + b2[tid + 256];
    out[b * 768 + tid + 512] = (f2 - mean) * rstd * g2[tid + 512] + b2[tid + 512];
}

// ---------- host ----------
extern "C" void kernel_launch(void* const* d_in, const int* in_sizes, int n_in,
                              void* d_out, int out_size, void* d_ws, size_t ws_size,
                              hipStream_t stream) {
    (void)in_sizes; (void)n_in; (void)out_size;
    const float* vf = (const float*)d_in[0];
    const float* tf = (const float*)d_in[1];
    const int* vmask = (const int*)d_in[2];
    const int* tmask = (const int*)d_in[3];
    const float* Wq = (const float*)d_in[4];
    const float* bq = (const float*)d_in[5];
    const float* Wk = (const float*)d_in[6];
    const float* bk = (const float*)d_in[7];
    const float* Wv = (const float*)d_in[8];
    const float* bv = (const float*)d_in[9];
    const float* Wo = (const float*)d_in[10];
    const float* bo = (const float*)d_in[11];
    const float* g1 = (const float*)d_in[12];
    const float* b1 = (const float*)d_in[13];
    const float* Wf = (const float*)d_in[14];
    const float* bfv = (const float*)d_in[15];
    const float* g2 = (const float*)d_in[16];
    const float* b2 = (const float*)d_in[17];
    float* outp = (float*)d_out;

    // footprint = 4,826,112 + CH * (2,359,296 X + 7,077,888 QKV + 2,359,296 VtG)
    int CH = 16;
    while (CH > 1 && 4826112ull + (size_t)CH * 11796480ull > ws_size) CH >>= 1;
    const int NC = 16 / CH;
    const int Rtot = CH * 1536;

    char* ws = (char*)d_ws;
    u16*   wsW      = (u16*)(ws);
    u16*   wsWo     = (u16*)(ws + 3538944);
    float* wsBqkv   = (float*)(ws + 4718592);
    float* wsPooled = (float*)(ws + 4727808);
    u16*   wsX      = (u16*)(ws + 4826112);                 // [R][768] bf16 (reused: attn out)
    char*  qkvBase  = ws + 4826112 + (size_t)CH * 2359296;
    u16*   wsQKV    = (u16*)qkvBase;                         // [R][2304] bf16 (reused: Oproj bf16)
    u16*   wsOproj  = (u16*)qkvBase;
    u16*   wsVtG    = (u16*)(qkvBase + (size_t)CH * 7077888);// [768][R] bf16
    u16*   wsAttn   = wsX;

    k_transpose<<<dim3(144), dim3(256), 0, stream>>>(Wq, wsW, 768, 768);
    k_transpose<<<dim3(144), dim3(256), 0, stream>>>(Wk, wsW + 589824, 768, 768);
    k_transpose<<<dim3(144), dim3(256), 0, stream>>>(Wv, wsW + 1179648, 768, 768);
    k_transpose<<<dim3(144), dim3(256), 0, stream>>>(Wo, wsWo, 768, 768);
    k_bias<<<dim3(9), dim3(256), 0, stream>>>(bq, bk, bv, wsBqkv);
    k_zero<<<dim3(96), dim3(256), 0, stream>>>(wsPooled);

    for (int c = 0; c < NC; ++c) {
        const float* vfc = vf + (size_t)c * CH * 1024 * 768;
        const float* tfc = tf + (size_t)c * CH * 512 * 768;
        const int* vmc = vmask + c * CH * 1024;
        const int* tmc = tmask + c * CH * 512;

        k_cvt_x<<<dim3(CH * 1152), dim3(256), 0, stream>>>(vfc, tfc, wsX, CH * 196608);

        // QKV GEMM (256x128 tiles); V third written transposed directly into VtG
        k_gemm<true, false, true><<<dim3(CH * 108), dim3(512), 0, stream>>>(
            wsX, wsW, wsBqkv, nullptr, nullptr, (void*)wsQKV, 2304, 768, 0, wsVtG, Rtot);

        k_attn<<<dim3(CH * 16), dim3(512), 0, stream>>>(
            wsQKV, wsVtG, vmc, tmc, wsAttn, CH, Rtot);

        // O-proj + bias + residual, bf16 out
        k_gemm<true, true, false><<<dim3(CH * 36), dim3(512), 0, stream>>>(
            wsAttn, wsWo, bo, vfc, tfc, (void*)wsOproj, 768, 768, CH * 1024, nullptr, 0);

        k_ln_pool<<<dim3(CH * 48), dim3(256), 0, stream>>>(
            wsOproj, vmc, tmc, g1, b1, wsPooled, CH * 1024, c * CH);
    }

    k_final<<<dim3(16), dim3(256), 0, stream>>>(wsPooled, vmask, tmask, Wf, bfv, g2, b2, outp);
}